// Round 10
// baseline (504.804 us; speedup 1.0000x reference)
//
#include <hip/hip_runtime.h>
#include <stdint.h>

#define N_NODES 100000
#define N_EDGES 600000
#define DIM_H   128
#define DIM_OUT 64
#define WPAD    136      // padded LDS row stride in ushort units (272B)
#define BN_EPS  1e-5f
#define NBLK    391      // ceil(N_NODES/256)
#define GRID64_HEAD 1563 // ceil(N_NODES/64)
#define MLP_GRID 782

typedef __attribute__((ext_vector_type(8))) __bf16        bh8;
typedef __attribute__((ext_vector_type(4))) float         fl4;
typedef __attribute__((ext_vector_type(8))) unsigned short us8;
typedef __attribute__((ext_vector_type(4))) unsigned short us4;

__device__ __forceinline__ unsigned short f2bfbits(float f) {
  unsigned int u = __builtin_bit_cast(unsigned int, f);
  u += 0x7fffu + ((u >> 16) & 1u);           // RNE
  return (unsigned short)(u >> 16);
}
__device__ __forceinline__ float bf2f(unsigned short b) {
  unsigned int u = ((unsigned int)b) << 16;
  return __builtin_bit_cast(float, u);
}
// in-wave LDS producer->consumer fence (lanes of the same wave only)
__device__ __forceinline__ void wave_lds_fence() {
  asm volatile("s_waitcnt lgkmcnt(0)" ::: "memory");
  __builtin_amdgcn_sched_barrier(0);
}

// ---------------- weight prep (fragment-linear layout) + zero stats/deg/tickets ----------------
__global__ void prep_kernel(const float* __restrict__ cw1, const float* __restrict__ cw2,
                            const float* __restrict__ fc1w, const float* __restrict__ fc2w,
                            unsigned short* __restrict__ W1F, unsigned short* __restrict__ W2F,
                            unsigned short* __restrict__ F1F, unsigned short* __restrict__ F2F,
                            float* __restrict__ stats, int* __restrict__ deg,
                            int* __restrict__ tickets) {
  int t = blockIdx.x * 256 + threadIdx.x;
  if (t < 3 * 16384) {
    int l = t >> 14, o = t & 16383;
    int j = o & 7, lane = (o >> 3) & 63, kk = (o >> 9) & 3, n0 = o >> 11;
    int k = kk * 32 + ((lane >> 4) << 3) + j;
    int n = (n0 << 4) + (lane & 15);
    W1F[t] = f2bfbits(cw1[l * 16384 + k * 128 + n]);
    W2F[t] = f2bfbits(cw2[l * 16384 + k * 128 + n]);
  }
  if (t < 16384) {
    int o = t;
    int j = o & 7, lane = (o >> 3) & 63, kk = (o >> 9) & 3, n0 = o >> 11;
    int k = kk * 32 + ((lane >> 4) << 3) + j;
    int n = (n0 << 4) + (lane & 15);
    F1F[t] = f2bfbits(fc1w[k * 128 + n]);
  }
  if (t < 8192) {
    int o = t;
    int j = o & 7, lane = (o >> 3) & 63, kk = (o >> 9) & 3, n0 = o >> 11;
    int k = kk * 32 + ((lane >> 4) << 3) + j;
    int n = (n0 << 4) + (lane & 15);                 // n < 64
    F2F[t] = f2bfbits(fc2w[k * 64 + n]);
  }
  if (t < 768)   stats[t] = 0.f;
  if (t < 4)     tickets[t] = 0;
  if (t < N_NODES) deg[t] = 0;
}

// ---------------- x->bf16 cast + degree count + dropout bitmask pack ----------------
__global__ void deg_xcast(const float* __restrict__ x, unsigned short* __restrict__ xB,
                          const int* __restrict__ ei, int* __restrict__ deg,
                          const float* __restrict__ mask, unsigned int* __restrict__ bmask) {
  int i = blockIdx.x * 256 + threadIdx.x;    // 3.2M fl4 chunks exactly
  fl4 v = reinterpret_cast<const fl4*>(x)[i];
  us4 p;
#pragma unroll
  for (int j = 0; j < 4; ++j) p[j] = f2bfbits(v[j]);
  reinterpret_cast<us4*>(xB)[i] = p;
  if (i < N_EDGES) atomicAdd(&deg[ei[N_EDGES + i]], 1);
  if (i < N_NODES * 4) {                     // one dword of bitmask = 32 cols
    const float* mp = mask + (long)i * 32;
    unsigned int b = 0;
#pragma unroll
    for (int j8 = 0; j8 < 8; ++j8) {
      fl4 mv = *reinterpret_cast<const fl4*>(mp + j8 * 4);
      b |= (mv[0] > 0.f ? 1u : 0u) << (j8 * 4 + 0);
      b |= (mv[1] > 0.f ? 1u : 0u) << (j8 * 4 + 1);
      b |= (mv[2] > 0.f ? 1u : 0u) << (j8 * 4 + 2);
      b |= (mv[3] > 0.f ? 1u : 0u) << (j8 * 4 + 3);
    }
    bmask[i] = b;
  }
}

// ---------------- CSR build ----------------
__global__ void scanA(const int* __restrict__ deg, int* __restrict__ rowstart,
                      int* __restrict__ bsum) {
  __shared__ int s[256];
  int t = threadIdx.x, i = blockIdx.x * 256 + t;
  int v = (i < N_NODES) ? deg[i] : 0;
  s[t] = v;
  __syncthreads();
#pragma unroll
  for (int off = 1; off < 256; off <<= 1) {
    int u = (t >= off) ? s[t - off] : 0;
    __syncthreads();
    s[t] += u;
    __syncthreads();
  }
  if (i < N_NODES) rowstart[i] = s[t] - v;
  if (t == 0) bsum[blockIdx.x] = s[255];
}

// scanC with inline block-offset computation (replaces scanB)
__global__ void scanC(int* __restrict__ rowstart, const int* __restrict__ bsum,
                      int* __restrict__ cursor) {
  __shared__ int sred[256];
  int b = blockIdx.x, t = threadIdx.x;
  int partial = 0;
  for (int j = t; j < b; j += 256) partial += bsum[j];
  sred[t] = partial;
  __syncthreads();
#pragma unroll
  for (int off = 128; off > 0; off >>= 1) {
    if (t < off) sred[t] += sred[t + off];
    __syncthreads();
  }
  int boffb = sred[0];
  int i = b * 256 + t;
  if (i < N_NODES) {
    int v = rowstart[i] + boffb;
    rowstart[i] = v;
    cursor[i] = v;
  }
  if (i == 0) rowstart[N_NODES] = N_EDGES;
}

__global__ void csr_fill(const int* __restrict__ ei, int* __restrict__ cursor,
                         int* __restrict__ csr_src) {
  int e = blockIdx.x * 256 + threadIdx.x;
  if (e < N_EDGES) {
    int pos = atomicAdd(&cursor[ei[N_EDGES + e]], 1);
    csr_src[pos] = ei[e];
  }
}

// ---------------- gather: one node per wave; quarter-wave = one 256B row ----------------
// AFFINE=0: agg = sum over {i}∪N(i) of H_j
// AFFINE=1: agg = s*sum(H_j) + cnt*b  with precomputed sb (s=sb[0:128], b=sb[128:256])
template <int AFFINE>
__global__ __launch_bounds__(256)
void gather_h(const unsigned short* __restrict__ H, const float* __restrict__ sb,
              const int* __restrict__ rowstart, const int* __restrict__ csr,
              unsigned short* __restrict__ aggB) {
  int node = blockIdx.x * 4 + (threadIdx.x >> 6);   // grid*4 == N_NODES exactly
  int lane = threadIdx.x & 63;
  int q = lane >> 4, lc = lane & 15;
  int c = lc * 8;                        // 8 bf16 cols/lane; 16 lanes cover the row

  fl4 scA, scB, bcA, bcB;
  if (AFFINE) {
    scA = *reinterpret_cast<const fl4*>(sb + c);
    scB = *reinterpret_cast<const fl4*>(sb + c + 4);
    bcA = *reinterpret_cast<const fl4*>(sb + 128 + c);
    bcB = *reinterpret_cast<const fl4*>(sb + 128 + c + 4);
  }

  int nodeu = __builtin_amdgcn_readfirstlane(node);  // wave-uniform -> SGPR loads
  int rs = rowstart[nodeu], re = rowstart[nodeu + 1];
  int cnt = re - rs + 1;                 // {self} + neighbors
  float acc[8] = {0.f, 0.f, 0.f, 0.f, 0.f, 0.f, 0.f, 0.f};

  for (int base = 0; base < cnt; base += 64) {
    int item = base + lane;
    int myidx = (item == 0) ? nodeu : ((item < cnt) ? csr[rs + item - 1] : 0);
    int lim = cnt - base; if (lim > 64) lim = 64;
    for (int sub = 0; sub < lim; sub += 8) {
      int m0 = sub + q, m1 = sub + 4 + q;
      int i0 = __shfl(myidx, m0);
      int i1 = __shfl(myidx, m1);
      us8 r0 = (us8)0, r1 = (us8)0;
      if (m0 < lim) r0 = *reinterpret_cast<const us8*>(H + (long)i0 * DIM_H + c);
      if (m1 < lim) r1 = *reinterpret_cast<const us8*>(H + (long)i1 * DIM_H + c);
#pragma unroll
      for (int j = 0; j < 8; ++j) acc[j] += bf2f(r0[j]) + bf2f(r1[j]);
    }
  }

#pragma unroll
  for (int j = 0; j < 8; ++j) {
    acc[j] += __shfl_xor(acc[j], 16);
    acc[j] += __shfl_xor(acc[j], 32);
  }

  if (q == 0) {
    us8 pk;
    if (AFFINE) {
      float fc = (float)cnt;
#pragma unroll
      for (int j = 0; j < 4; ++j) {
        pk[j]     = f2bfbits(scA[j] * acc[j]     + fc * bcA[j]);
        pk[4 + j] = f2bfbits(scB[j] * acc[4 + j] + fc * bcB[j]);
      }
    } else {
#pragma unroll
      for (int j = 0; j < 8; ++j) pk[j] = f2bfbits(acc[j]);
    }
    *reinterpret_cast<us8*>(aggB + (long)node * DIM_H + c) = pk;
  }
}

// ---------------- fused GIN MLP + last-block BN finalize (sb_out) ----------------
__global__ __launch_bounds__(256, 4)
void mlp_kernel(const unsigned short* __restrict__ A,
                const unsigned short* __restrict__ W1F, const float* __restrict__ b1,
                const unsigned short* __restrict__ W2F, const float* __restrict__ b2,
                unsigned short* __restrict__ Z, float* __restrict__ stats,
                const float* __restrict__ gamma, const float* __restrict__ beta,
                float* __restrict__ sb_out, int* __restrict__ ticket) {
  __shared__ __align__(16) unsigned short ybuf[128 * WPAD];   // 34816 B
  __shared__ float red[4][2][128];                            //  4096 B
  __shared__ int lastflag;

  const int tid = threadIdx.x;
  const int wid = tid >> 6, lane = tid & 63;
  const int lr = lane & 15, lg = lane >> 4;
  const int row0 = blockIdx.x * 128;

  // A fragments straight from bf16 global
  bh8 afrag[2][4];
#pragma unroll
  for (int rt = 0; rt < 2; ++rt) {
    int row = row0 + wid * 32 + rt * 16 + lr;
    bool valid = row < N_NODES;
    const unsigned short* ap = A + (long)row * DIM_H;
#pragma unroll
    for (int kk = 0; kk < 4; ++kk) {
      us8 t = (us8)0;
      if (valid) t = *reinterpret_cast<const us8*>(ap + kk * 32 + 8 * lg);
      afrag[rt][kk] = __builtin_bit_cast(bh8, t);
    }
  }

  // GEMM1 + bias + relu -> ybuf (bf16); B-fragments: contiguous 1KB burst per (n0,kk)
#pragma unroll
  for (int n0 = 0; n0 < 8; ++n0) {
    fl4 acc[2] = {{0,0,0,0},{0,0,0,0}};
#pragma unroll
    for (int kk = 0; kk < 4; ++kk) {
      bh8 b = *reinterpret_cast<const bh8*>(&W1F[((n0 * 4 + kk) << 9) + lane * 8]);
      acc[0] = __builtin_amdgcn_mfma_f32_16x16x32_bf16(afrag[0][kk], b, acc[0], 0, 0, 0);
      acc[1] = __builtin_amdgcn_mfma_f32_16x16x32_bf16(afrag[1][kk], b, acc[1], 0, 0, 0);
    }
    float bias = b1[n0 * 16 + lr];
#pragma unroll
    for (int rt = 0; rt < 2; ++rt)
#pragma unroll
      for (int r = 0; r < 4; ++r) {
        float v = acc[rt][r] + bias;
        v = v > 0.f ? v : 0.f;
        ybuf[(wid * 32 + rt * 16 + 4 * lg + r) * WPAD + n0 * 16 + lr] = f2bfbits(v);
      }
  }

  wave_lds_fence();          // own-wave rows only

  // A2 fragments from ybuf
  bh8 a2[2][4];
#pragma unroll
  for (int rt = 0; rt < 2; ++rt)
#pragma unroll
    for (int kk = 0; kk < 4; ++kk)
      a2[rt][kk] = *reinterpret_cast<const bh8*>(
          &ybuf[(wid * 32 + rt * 16 + lr) * WPAD + kk * 32 + 8 * lg]);

  wave_lds_fence();          // a2 in regs before ybuf overwrite

  // GEMM2 + bias + relu -> ybuf (z), accumulate BN stats
#pragma unroll
  for (int n0 = 0; n0 < 8; ++n0) {
    fl4 acc[2] = {{0,0,0,0},{0,0,0,0}};
#pragma unroll
    for (int kk = 0; kk < 4; ++kk) {
      bh8 b = *reinterpret_cast<const bh8*>(&W2F[((n0 * 4 + kk) << 9) + lane * 8]);
      acc[0] = __builtin_amdgcn_mfma_f32_16x16x32_bf16(a2[0][kk], b, acc[0], 0, 0, 0);
      acc[1] = __builtin_amdgcn_mfma_f32_16x16x32_bf16(a2[1][kk], b, acc[1], 0, 0, 0);
    }
    float bias = b2[n0 * 16 + lr];
    float sp = 0.f, qp = 0.f;
#pragma unroll
    for (int rt = 0; rt < 2; ++rt)
#pragma unroll
      for (int r = 0; r < 4; ++r) {
        int row = row0 + wid * 32 + rt * 16 + 4 * lg + r;
        float v = acc[rt][r] + bias;
        v = v > 0.f ? v : 0.f;
        ybuf[(wid * 32 + rt * 16 + 4 * lg + r) * WPAD + n0 * 16 + lr] = f2bfbits(v);
        if (row < N_NODES) { sp += v; qp += v * v; }
      }
    sp += __shfl_xor(sp, 16); sp += __shfl_xor(sp, 32);
    qp += __shfl_xor(qp, 16); qp += __shfl_xor(qp, 32);
    if (lg == 0) { red[wid][0][n0 * 16 + lr] = sp; red[wid][1][n0 * 16 + lr] = qp; }
  }

  wave_lds_fence();

  // per-wave coalesced z store (own 32 rows)
#pragma unroll
  for (int i = 0; i < 8; ++i) {
    int ch = i * 64 + lane;               // 0..511
    int r  = wid * 32 + (ch >> 4);
    int c8 = (ch & 15) << 3;
    int row = row0 + r;
    if (row < N_NODES)
      *reinterpret_cast<uint4*>(&Z[(long)row * DIM_H + c8]) =
          *reinterpret_cast<const uint4*>(&ybuf[r * WPAD + c8]);
  }

  __syncthreads();           // cross-wave stats reduce

  {
    int which = tid >> 7, cc = tid & 127;
    float v = red[0][which][cc] + red[1][which][cc] + red[2][which][cc] + red[3][which][cc];
    unsafeAtomicAdd(&stats[which * 128 + cc], v);
  }

  // ---- last block computes sb (BN scale/bias) for the next consumer ----
  __threadfence();
  __syncthreads();
  if (tid == 0) {
    int old = atomicAdd(ticket, 1);
    lastflag = (old == (int)gridDim.x - 1) ? 1 : 0;
    if (lastflag) *ticket = 0;           // self-clean for next replay
  }
  __syncthreads();
  if (lastflag && tid < 128) {
    __threadfence();
    float s  = __hip_atomic_load(&stats[tid], __ATOMIC_RELAXED, __HIP_MEMORY_SCOPE_AGENT);
    float ss = __hip_atomic_load(&stats[128 + tid], __ATOMIC_RELAXED, __HIP_MEMORY_SCOPE_AGENT);
    const float inv_n = 1.0f / (float)N_NODES;
    float mean = s * inv_n;
    float var  = ss * inv_n - mean * mean;
    float sc = gamma[tid] * rsqrtf(var + BN_EPS);
    sb_out[tid] = sc;
    sb_out[128 + tid] = beta[tid] - mean * sc;
  }
}

// ---------------- head: BN-affine(sb) -> fc1 -> relu -> dropout(bitmask) -> fc2 -> log_softmax --
__global__ __launch_bounds__(256, 6)
void head_kernel(const unsigned short* __restrict__ Z, const float* __restrict__ sb,
                 const unsigned short* __restrict__ F1F, const float* __restrict__ fc1b,
                 const unsigned short* __restrict__ F2F, const float* __restrict__ fc2b,
                 const unsigned int* __restrict__ bmask, float* __restrict__ out) {
  __shared__ __align__(16) unsigned short ybuf[64 * WPAD];    // 17408 B

  const int tid = threadIdx.x;
  const int wid = tid >> 6, lane = tid & 63;
  const int lr = lane & 15, lg = lane >> 4;
  const int row0 = blockIdx.x * 64;

  // dropout bitmask for this lane's 4 output rows (128 bits each)
  unsigned int bw[4][4];
#pragma unroll
  for (int r = 0; r < 4; ++r) {
    int row = row0 + wid * 16 + 4 * lg + r;
    if (row < N_NODES) {
      uint4 t = *reinterpret_cast<const uint4*>(bmask + (long)row * 4);
      bw[r][0] = t.x; bw[r][1] = t.y; bw[r][2] = t.z; bw[r][3] = t.w;
    } else {
      bw[r][0] = bw[r][1] = bw[r][2] = bw[r][3] = 0u;
    }
  }

  // A fragments: affine(z) in bf16 with precomputed sb
  bh8 afrag[4];
#pragma unroll
  for (int kk = 0; kk < 4; ++kk) {
    int k0 = kk * 32 + 8 * lg;
    fl4 s0  = *reinterpret_cast<const fl4*>(sb + k0);
    fl4 s1  = *reinterpret_cast<const fl4*>(sb + k0 + 4);
    fl4 bb0 = *reinterpret_cast<const fl4*>(sb + 128 + k0);
    fl4 bb1 = *reinterpret_cast<const fl4*>(sb + 128 + k0 + 4);
    int row = row0 + wid * 16 + lr;
    us8 t = (us8)0;
    if (row < N_NODES) {
      us8 zv = *reinterpret_cast<const us8*>(Z + (long)row * DIM_H + k0);
#pragma unroll
      for (int j = 0; j < 4; ++j) {
        t[j]     = f2bfbits(bf2f(zv[j])     * s0[j] + bb0[j]);
        t[4 + j] = f2bfbits(bf2f(zv[4 + j]) * s1[j] + bb1[j]);
      }
    }
    afrag[kk] = __builtin_bit_cast(bh8, t);
  }

  // GEMM1 + fc1b + relu + dropout -> ybuf
#pragma unroll
  for (int n0 = 0; n0 < 8; ++n0) {
    fl4 acc = {0.f, 0.f, 0.f, 0.f};
#pragma unroll
    for (int kk = 0; kk < 4; ++kk) {
      bh8 b = *reinterpret_cast<const bh8*>(&F1F[((n0 * 4 + kk) << 9) + lane * 8]);
      acc = __builtin_amdgcn_mfma_f32_16x16x32_bf16(afrag[kk], b, acc, 0, 0, 0);
    }
    float bias = fc1b[n0 * 16 + lr];
#pragma unroll
    for (int r = 0; r < 4; ++r) {
      float v = acc[r] + bias;
      v = v > 0.f ? v : 0.f;
      float mk = ((bw[r][n0 >> 1] >> (((n0 & 1) << 4) + lr)) & 1u) ? 2.0f : 0.0f;
      ybuf[(wid * 16 + 4 * lg + r) * WPAD + n0 * 16 + lr] = f2bfbits(v * mk);
    }
  }
  wave_lds_fence();

  bh8 a2[4];
#pragma unroll
  for (int kk = 0; kk < 4; ++kk)
    a2[kk] = *reinterpret_cast<const bh8*>(
        &ybuf[(wid * 16 + lr) * WPAD + kk * 32 + 8 * lg]);

  // GEMM2 (N=64)
  fl4 acc2[4];
#pragma unroll
  for (int n0 = 0; n0 < 4; ++n0) {
    acc2[n0] = (fl4){0.f, 0.f, 0.f, 0.f};
#pragma unroll
    for (int kk = 0; kk < 4; ++kk) {
      bh8 b = *reinterpret_cast<const bh8*>(&F2F[((n0 * 4 + kk) << 9) + lane * 8]);
      acc2[n0] = __builtin_amdgcn_mfma_f32_16x16x32_bf16(a2[kk], b, acc2[n0], 0, 0, 0);
    }
    float bias = fc2b[n0 * 16 + lr];
#pragma unroll
    for (int r = 0; r < 4; ++r) acc2[n0][r] += bias;
  }

  // log_softmax over 64 cols + store
#pragma unroll
  for (int r = 0; r < 4; ++r) {
    float m = fmaxf(fmaxf(acc2[0][r], acc2[1][r]), fmaxf(acc2[2][r], acc2[3][r]));
#pragma unroll
    for (int d = 1; d < 16; d <<= 1) m = fmaxf(m, __shfl_xor(m, d, 16));
    float se = 0.f;
#pragma unroll
    for (int n0 = 0; n0 < 4; ++n0) se += __expf(acc2[n0][r] - m);
#pragma unroll
    for (int d = 1; d < 16; d <<= 1) se += __shfl_xor(se, d, 16);
    float lse = m + __logf(se);
    int row = row0 + wid * 16 + 4 * lg + r;
    if (row < N_NODES) {
#pragma unroll
      for (int n0 = 0; n0 < 4; ++n0)
        out[(long)row * DIM_OUT + n0 * 16 + lr] = acc2[n0][r] - lse;
    }
  }
}

// ---------------- launcher ----------------
extern "C" void kernel_launch(void* const* d_in, const int* in_sizes, int n_in,
                              void* d_out, int out_size, void* d_ws, size_t ws_size,
                              hipStream_t stream) {
  const float* x      = (const float*)d_in[0];
  const int*   ei     = (const int*)d_in[1];
  const float* cw1    = (const float*)d_in[2];
  const float* cb1    = (const float*)d_in[3];
  const float* cw2    = (const float*)d_in[4];
  const float* cb2    = (const float*)d_in[5];
  const float* gamma  = (const float*)d_in[6];
  const float* beta   = (const float*)d_in[7];
  const float* fc1w   = (const float*)d_in[8];
  const float* fc1b   = (const float*)d_in[9];
  const float* fc2w   = (const float*)d_in[10];
  const float* fc2b   = (const float*)d_in[11];
  const float* mask   = (const float*)d_in[12];
  float* out = (float*)d_out;

  char* ws = (char*)d_ws;
  unsigned short* aggB  = (unsigned short*)ws;                 // 25,600,000 B
  unsigned short* Zb    = (unsigned short*)(ws + 25600000);    // 25,600,000 B (xB alias)
  unsigned short* W1F   = (unsigned short*)(ws + 51200000);    //     98,304 B
  unsigned short* W2F   = (unsigned short*)(ws + 51298304);    //     98,304 B
  unsigned short* F1F   = (unsigned short*)(ws + 51396608);    //     32,768 B
  unsigned short* F2F   = (unsigned short*)(ws + 51429376);    //     16,384 B
  float*          stats = (float*)(ws + 51445760);             //      3,072 B
  int*            rowst = (int*)(ws + 51448832);               //    400,004 B
  int*            cursor= (int*)(ws + 51848836);               //    400,000 B
  int*            csr   = (int*)(ws + 52248836);               //  2,400,000 B
  int*            bsum  = (int*)(ws + 54648836);               //      1,564 B
  unsigned int*   bmask = (unsigned int*)(ws + 54651968);      //  1,600,000 B
  float*          sb    = (float*)(ws + 56251968);             //      3,072 B (3x256)
  int*            tickets=(int*)(ws + 56255040);               //         16 B
  if (ws_size < 56255056u) return;

  prep_kernel<<<NBLK, 256, 0, stream>>>(cw1, cw2, fc1w, fc2w, W1F, W2F, F1F, F2F,
                                        stats, cursor, tickets);  // cursor doubles as deg
  deg_xcast<<<12500, 256, 0, stream>>>(x, Zb, ei, cursor, mask, bmask); // xB -> Zb

  scanA<<<NBLK, 256, 0, stream>>>(cursor, rowst, bsum);
  scanC<<<NBLK, 256, 0, stream>>>(rowst, bsum, cursor);
  csr_fill<<<2344, 256, 0, stream>>>(ei, cursor, csr);

  // layer 0: gather bf16 x (in Zb) -> aggB; mlp overwrites Zb (xB dead), emits sb0
  gather_h<0><<<25000, 256, 0, stream>>>(Zb, nullptr, rowst, csr, aggB);
  mlp_kernel<<<MLP_GRID, 256, 0, stream>>>(aggB, W1F, cb1, W2F, cb2, Zb, stats,
                                           gamma, beta, sb, tickets);

  // layer 1: uses sb0; emits sb1
  gather_h<1><<<25000, 256, 0, stream>>>(Zb, sb, rowst, csr, aggB);
  mlp_kernel<<<MLP_GRID, 256, 0, stream>>>(aggB, W1F + 16384, cb1 + 128, W2F + 16384,
                                           cb2 + 128, Zb, stats + 256,
                                           gamma + 128, beta + 128, sb + 256, tickets + 1);

  // layer 2: uses sb1; emits sb2
  gather_h<1><<<25000, 256, 0, stream>>>(Zb, sb + 256, rowst, csr, aggB);
  mlp_kernel<<<MLP_GRID, 256, 0, stream>>>(aggB, W1F + 32768, cb1 + 256, W2F + 32768,
                                           cb2 + 256, Zb, stats + 512,
                                           gamma + 256, beta + 256, sb + 512, tickets + 2);

  // head: uses sb2
  head_kernel<<<GRID64_HEAD, 256, 0, stream>>>(Zb, sb + 512,
                                               F1F, fc1b, F2F, fc2b, bmask, out);
}

// Round 11
// 315.039 us; speedup vs baseline: 1.6024x; 1.6024x over previous
//
#include <hip/hip_runtime.h>
#include <stdint.h>

#define N_NODES 100000
#define N_EDGES 600000
#define DIM_H   128
#define DIM_OUT 64
#define WPAD    136      // padded LDS row stride in ushort units (272B)
#define BN_EPS  1e-5f
#define NBLK    391      // ceil(N_NODES/256)
#define GRID64_HEAD 1563 // ceil(N_NODES/64)
#define MLP_GRID 782

typedef __attribute__((ext_vector_type(8))) __bf16        bh8;
typedef __attribute__((ext_vector_type(4))) float         fl4;
typedef __attribute__((ext_vector_type(8))) unsigned short us8;
typedef __attribute__((ext_vector_type(4))) unsigned short us4;

__device__ __forceinline__ unsigned short f2bfbits(float f) {
  unsigned int u = __builtin_bit_cast(unsigned int, f);
  u += 0x7fffu + ((u >> 16) & 1u);           // RNE
  return (unsigned short)(u >> 16);
}
__device__ __forceinline__ float bf2f(unsigned short b) {
  unsigned int u = ((unsigned int)b) << 16;
  return __builtin_bit_cast(float, u);
}
// in-wave LDS producer->consumer fence (lanes of the same wave only)
__device__ __forceinline__ void wave_lds_fence() {
  asm volatile("s_waitcnt lgkmcnt(0)" ::: "memory");
  __builtin_amdgcn_sched_barrier(0);
}

// ---------------- weight prep (fragment-linear layout) + zero stats/deg ----------------
__global__ void prep_kernel(const float* __restrict__ cw1, const float* __restrict__ cw2,
                            const float* __restrict__ fc1w, const float* __restrict__ fc2w,
                            unsigned short* __restrict__ W1F, unsigned short* __restrict__ W2F,
                            unsigned short* __restrict__ F1F, unsigned short* __restrict__ F2F,
                            float* __restrict__ stats, int* __restrict__ deg) {
  int t = blockIdx.x * 256 + threadIdx.x;
  if (t < 3 * 16384) {
    int l = t >> 14, o = t & 16383;
    int j = o & 7, lane = (o >> 3) & 63, kk = (o >> 9) & 3, n0 = o >> 11;
    int k = kk * 32 + ((lane >> 4) << 3) + j;
    int n = (n0 << 4) + (lane & 15);
    W1F[t] = f2bfbits(cw1[l * 16384 + k * 128 + n]);
    W2F[t] = f2bfbits(cw2[l * 16384 + k * 128 + n]);
  }
  if (t < 16384) {
    int o = t;
    int j = o & 7, lane = (o >> 3) & 63, kk = (o >> 9) & 3, n0 = o >> 11;
    int k = kk * 32 + ((lane >> 4) << 3) + j;
    int n = (n0 << 4) + (lane & 15);
    F1F[t] = f2bfbits(fc1w[k * 128 + n]);
  }
  if (t < 8192) {
    int o = t;
    int j = o & 7, lane = (o >> 3) & 63, kk = (o >> 9) & 3, n0 = o >> 11;
    int k = kk * 32 + ((lane >> 4) << 3) + j;
    int n = (n0 << 4) + (lane & 15);                 // n < 64
    F2F[t] = f2bfbits(fc2w[k * 64 + n]);
  }
  if (t < 768)   stats[t] = 0.f;
  if (t < N_NODES) deg[t] = 0;
}

// ---------------- x->bf16 cast + degree count + dropout bitmask pack ----------------
__global__ void deg_xcast(const float* __restrict__ x, unsigned short* __restrict__ xB,
                          const int* __restrict__ ei, int* __restrict__ deg,
                          const float* __restrict__ mask, unsigned int* __restrict__ bmask) {
  int i = blockIdx.x * 256 + threadIdx.x;    // 3.2M fl4 chunks exactly
  fl4 v = reinterpret_cast<const fl4*>(x)[i];
  us4 p;
#pragma unroll
  for (int j = 0; j < 4; ++j) p[j] = f2bfbits(v[j]);
  reinterpret_cast<us4*>(xB)[i] = p;
  if (i < N_EDGES) atomicAdd(&deg[ei[N_EDGES + i]], 1);
  if (i < N_NODES * 4) {                     // one dword of bitmask = 32 cols
    const float* mp = mask + (long)i * 32;
    unsigned int b = 0;
#pragma unroll
    for (int j8 = 0; j8 < 8; ++j8) {
      fl4 mv = *reinterpret_cast<const fl4*>(mp + j8 * 4);
      b |= (mv[0] > 0.f ? 1u : 0u) << (j8 * 4 + 0);
      b |= (mv[1] > 0.f ? 1u : 0u) << (j8 * 4 + 1);
      b |= (mv[2] > 0.f ? 1u : 0u) << (j8 * 4 + 2);
      b |= (mv[3] > 0.f ? 1u : 0u) << (j8 * 4 + 3);
    }
    bmask[i] = b;
  }
}

// ---------------- CSR build ----------------
__global__ void scanA(const int* __restrict__ deg, int* __restrict__ rowstart,
                      int* __restrict__ bsum) {
  __shared__ int s[256];
  int t = threadIdx.x, i = blockIdx.x * 256 + t;
  int v = (i < N_NODES) ? deg[i] : 0;
  s[t] = v;
  __syncthreads();
#pragma unroll
  for (int off = 1; off < 256; off <<= 1) {
    int u = (t >= off) ? s[t - off] : 0;
    __syncthreads();
    s[t] += u;
    __syncthreads();
  }
  if (i < N_NODES) rowstart[i] = s[t] - v;
  if (t == 0) bsum[blockIdx.x] = s[255];
}

// scanC with inline block-offset computation (replaces scanB)
__global__ void scanC(int* __restrict__ rowstart, const int* __restrict__ bsum,
                      int* __restrict__ cursor) {
  __shared__ int sred[256];
  int b = blockIdx.x, t = threadIdx.x;
  int partial = 0;
  for (int j = t; j < b; j += 256) partial += bsum[j];
  sred[t] = partial;
  __syncthreads();
#pragma unroll
  for (int off = 128; off > 0; off >>= 1) {
    if (t < off) sred[t] += sred[t + off];
    __syncthreads();
  }
  int boffb = sred[0];
  int i = b * 256 + t;
  if (i < N_NODES) {
    int v = rowstart[i] + boffb;
    rowstart[i] = v;
    cursor[i] = v;
  }
  if (i == 0) rowstart[N_NODES] = N_EDGES;
}

__global__ void csr_fill(const int* __restrict__ ei, int* __restrict__ cursor,
                         int* __restrict__ csr_src) {
  int e = blockIdx.x * 256 + threadIdx.x;
  if (e < N_EDGES) {
    int pos = atomicAdd(&cursor[ei[N_EDGES + e]], 1);
    csr_src[pos] = ei[e];
  }
}

// ---------------- BN finalize: sb[c]=gamma*rsqrt(var+eps); sb[128+c]=beta-mean*s ----------------
__global__ void bn_finalize(const float* __restrict__ stats, const float* __restrict__ gamma,
                            const float* __restrict__ beta, float* __restrict__ sb) {
  int c = threadIdx.x;
  const float inv_n = 1.0f / (float)N_NODES;
  float mean = stats[c] * inv_n;
  float var  = stats[128 + c] * inv_n - mean * mean;
  float s = gamma[c] * rsqrtf(var + BN_EPS);
  sb[c] = s;
  sb[128 + c] = beta[c] - mean * s;
}

// ---------------- gather: one node per wave; quarter-wave = one 256B row ----------------
// AFFINE=0: agg = sum over {i}∪N(i) of H_j
// AFFINE=1: agg = s*sum(H_j) + cnt*b  with precomputed sb (s=sb[0:128], b=sb[128:256])
template <int AFFINE>
__global__ __launch_bounds__(256)
void gather_h(const unsigned short* __restrict__ H, const float* __restrict__ sb,
              const int* __restrict__ rowstart, const int* __restrict__ csr,
              unsigned short* __restrict__ aggB) {
  int node = blockIdx.x * 4 + (threadIdx.x >> 6);   // grid*4 == N_NODES exactly
  int lane = threadIdx.x & 63;
  int q = lane >> 4, lc = lane & 15;
  int c = lc * 8;                        // 8 bf16 cols/lane; 16 lanes cover the row

  fl4 scA, scB, bcA, bcB;
  if (AFFINE) {
    scA = *reinterpret_cast<const fl4*>(sb + c);
    scB = *reinterpret_cast<const fl4*>(sb + c + 4);
    bcA = *reinterpret_cast<const fl4*>(sb + 128 + c);
    bcB = *reinterpret_cast<const fl4*>(sb + 128 + c + 4);
  }

  int nodeu = __builtin_amdgcn_readfirstlane(node);  // wave-uniform -> SGPR loads
  int rs = rowstart[nodeu], re = rowstart[nodeu + 1];
  int cnt = re - rs + 1;                 // {self} + neighbors
  float acc[8] = {0.f, 0.f, 0.f, 0.f, 0.f, 0.f, 0.f, 0.f};

  for (int base = 0; base < cnt; base += 64) {
    int item = base + lane;
    int myidx = (item == 0) ? nodeu : ((item < cnt) ? csr[rs + item - 1] : 0);
    int lim = cnt - base; if (lim > 64) lim = 64;
    for (int sub = 0; sub < lim; sub += 8) {
      int m0 = sub + q, m1 = sub + 4 + q;
      int i0 = __shfl(myidx, m0);
      int i1 = __shfl(myidx, m1);
      us8 r0 = (us8)0, r1 = (us8)0;
      if (m0 < lim) r0 = *reinterpret_cast<const us8*>(H + (long)i0 * DIM_H + c);
      if (m1 < lim) r1 = *reinterpret_cast<const us8*>(H + (long)i1 * DIM_H + c);
#pragma unroll
      for (int j = 0; j < 8; ++j) acc[j] += bf2f(r0[j]) + bf2f(r1[j]);
    }
  }

#pragma unroll
  for (int j = 0; j < 8; ++j) {
    acc[j] += __shfl_xor(acc[j], 16);
    acc[j] += __shfl_xor(acc[j], 32);
  }

  if (q == 0) {
    us8 pk;
    if (AFFINE) {
      float fc = (float)cnt;
#pragma unroll
      for (int j = 0; j < 4; ++j) {
        pk[j]     = f2bfbits(scA[j] * acc[j]     + fc * bcA[j]);
        pk[4 + j] = f2bfbits(scB[j] * acc[4 + j] + fc * bcB[j]);
      }
    } else {
#pragma unroll
      for (int j = 0; j < 8; ++j) pk[j] = f2bfbits(acc[j]);
    }
    *reinterpret_cast<us8*>(aggB + (long)node * DIM_H + c) = pk;
  }
}

// ---------------- fused GIN MLP: weights from L2 (fragment-linear), 4 blocks/CU ----------------
__global__ __launch_bounds__(256, 4)
void mlp_kernel(const unsigned short* __restrict__ A,
                const unsigned short* __restrict__ W1F, const float* __restrict__ b1,
                const unsigned short* __restrict__ W2F, const float* __restrict__ b2,
                unsigned short* __restrict__ Z, float* __restrict__ stats) {
  __shared__ __align__(16) unsigned short ybuf[128 * WPAD];   // 34816 B
  __shared__ float red[4][2][128];                            //  4096 B

  const int tid = threadIdx.x;
  const int wid = tid >> 6, lane = tid & 63;
  const int lr = lane & 15, lg = lane >> 4;
  const int row0 = blockIdx.x * 128;

  // A fragments straight from bf16 global
  bh8 afrag[2][4];
#pragma unroll
  for (int rt = 0; rt < 2; ++rt) {
    int row = row0 + wid * 32 + rt * 16 + lr;
    bool valid = row < N_NODES;
    const unsigned short* ap = A + (long)row * DIM_H;
#pragma unroll
    for (int kk = 0; kk < 4; ++kk) {
      us8 t = (us8)0;
      if (valid) t = *reinterpret_cast<const us8*>(ap + kk * 32 + 8 * lg);
      afrag[rt][kk] = __builtin_bit_cast(bh8, t);
    }
  }

  // GEMM1 + bias + relu -> ybuf (bf16); B-fragments: contiguous 1KB burst per (n0,kk)
#pragma unroll
  for (int n0 = 0; n0 < 8; ++n0) {
    fl4 acc[2] = {{0,0,0,0},{0,0,0,0}};
#pragma unroll
    for (int kk = 0; kk < 4; ++kk) {
      bh8 b = *reinterpret_cast<const bh8*>(&W1F[((n0 * 4 + kk) << 9) + lane * 8]);
      acc[0] = __builtin_amdgcn_mfma_f32_16x16x32_bf16(afrag[0][kk], b, acc[0], 0, 0, 0);
      acc[1] = __builtin_amdgcn_mfma_f32_16x16x32_bf16(afrag[1][kk], b, acc[1], 0, 0, 0);
    }
    float bias = b1[n0 * 16 + lr];
#pragma unroll
    for (int rt = 0; rt < 2; ++rt)
#pragma unroll
      for (int r = 0; r < 4; ++r) {
        float v = acc[rt][r] + bias;
        v = v > 0.f ? v : 0.f;
        ybuf[(wid * 32 + rt * 16 + 4 * lg + r) * WPAD + n0 * 16 + lr] = f2bfbits(v);
      }
  }

  wave_lds_fence();          // own-wave rows only

  // A2 fragments from ybuf
  bh8 a2[2][4];
#pragma unroll
  for (int rt = 0; rt < 2; ++rt)
#pragma unroll
    for (int kk = 0; kk < 4; ++kk)
      a2[rt][kk] = *reinterpret_cast<const bh8*>(
          &ybuf[(wid * 32 + rt * 16 + lr) * WPAD + kk * 32 + 8 * lg]);

  wave_lds_fence();          // a2 in regs before ybuf overwrite

  // GEMM2 + bias + relu -> ybuf (z), accumulate BN stats
#pragma unroll
  for (int n0 = 0; n0 < 8; ++n0) {
    fl4 acc[2] = {{0,0,0,0},{0,0,0,0}};
#pragma unroll
    for (int kk = 0; kk < 4; ++kk) {
      bh8 b = *reinterpret_cast<const bh8*>(&W2F[((n0 * 4 + kk) << 9) + lane * 8]);
      acc[0] = __builtin_amdgcn_mfma_f32_16x16x32_bf16(a2[0][kk], b, acc[0], 0, 0, 0);
      acc[1] = __builtin_amdgcn_mfma_f32_16x16x32_bf16(a2[1][kk], b, acc[1], 0, 0, 0);
    }
    float bias = b2[n0 * 16 + lr];
    float sp = 0.f, qp = 0.f;
#pragma unroll
    for (int rt = 0; rt < 2; ++rt)
#pragma unroll
      for (int r = 0; r < 4; ++r) {
        int row = row0 + wid * 32 + rt * 16 + 4 * lg + r;
        float v = acc[rt][r] + bias;
        v = v > 0.f ? v : 0.f;
        ybuf[(wid * 32 + rt * 16 + 4 * lg + r) * WPAD + n0 * 16 + lr] = f2bfbits(v);
        if (row < N_NODES) { sp += v; qp += v * v; }
      }
    sp += __shfl_xor(sp, 16); sp += __shfl_xor(sp, 32);
    qp += __shfl_xor(qp, 16); qp += __shfl_xor(qp, 32);
    if (lg == 0) { red[wid][0][n0 * 16 + lr] = sp; red[wid][1][n0 * 16 + lr] = qp; }
  }

  wave_lds_fence();

  // per-wave coalesced z store (own 32 rows)
#pragma unroll
  for (int i = 0; i < 8; ++i) {
    int ch = i * 64 + lane;               // 0..511
    int r  = wid * 32 + (ch >> 4);
    int c8 = (ch & 15) << 3;
    int row = row0 + r;
    if (row < N_NODES)
      *reinterpret_cast<uint4*>(&Z[(long)row * DIM_H + c8]) =
          *reinterpret_cast<const uint4*>(&ybuf[r * WPAD + c8]);
  }

  __syncthreads();           // only cross-wave dependency: stats reduce

  {
    int which = tid >> 7, cc = tid & 127;
    float v = red[0][which][cc] + red[1][which][cc] + red[2][which][cc] + red[3][which][cc];
    unsafeAtomicAdd(&stats[which * 128 + cc], v);
  }
}

// ---------------- head: BN-affine(sb) -> fc1 -> relu -> dropout(bitmask) -> fc2 -> log_softmax --
__global__ __launch_bounds__(256, 6)
void head_kernel(const unsigned short* __restrict__ Z, const float* __restrict__ sb,
                 const unsigned short* __restrict__ F1F, const float* __restrict__ fc1b,
                 const unsigned short* __restrict__ F2F, const float* __restrict__ fc2b,
                 const unsigned int* __restrict__ bmask, float* __restrict__ out) {
  __shared__ __align__(16) unsigned short ybuf[64 * WPAD];    // 17408 B

  const int tid = threadIdx.x;
  const int wid = tid >> 6, lane = tid & 63;
  const int lr = lane & 15, lg = lane >> 4;
  const int row0 = blockIdx.x * 64;

  // dropout bitmask for this lane's 4 output rows (128 bits each)
  unsigned int bw[4][4];
#pragma unroll
  for (int r = 0; r < 4; ++r) {
    int row = row0 + wid * 16 + 4 * lg + r;
    if (row < N_NODES) {
      uint4 t = *reinterpret_cast<const uint4*>(bmask + (long)row * 4);
      bw[r][0] = t.x; bw[r][1] = t.y; bw[r][2] = t.z; bw[r][3] = t.w;
    } else {
      bw[r][0] = bw[r][1] = bw[r][2] = bw[r][3] = 0u;
    }
  }

  // A fragments: affine(z) in bf16 with precomputed sb
  bh8 afrag[4];
#pragma unroll
  for (int kk = 0; kk < 4; ++kk) {
    int k0 = kk * 32 + 8 * lg;
    fl4 s0  = *reinterpret_cast<const fl4*>(sb + k0);
    fl4 s1  = *reinterpret_cast<const fl4*>(sb + k0 + 4);
    fl4 bb0 = *reinterpret_cast<const fl4*>(sb + 128 + k0);
    fl4 bb1 = *reinterpret_cast<const fl4*>(sb + 128 + k0 + 4);
    int row = row0 + wid * 16 + lr;
    us8 t = (us8)0;
    if (row < N_NODES) {
      us8 zv = *reinterpret_cast<const us8*>(Z + (long)row * DIM_H + k0);
#pragma unroll
      for (int j = 0; j < 4; ++j) {
        t[j]     = f2bfbits(bf2f(zv[j])     * s0[j] + bb0[j]);
        t[4 + j] = f2bfbits(bf2f(zv[4 + j]) * s1[j] + bb1[j]);
      }
    }
    afrag[kk] = __builtin_bit_cast(bh8, t);
  }

  // GEMM1 + fc1b + relu + dropout -> ybuf
#pragma unroll
  for (int n0 = 0; n0 < 8; ++n0) {
    fl4 acc = {0.f, 0.f, 0.f, 0.f};
#pragma unroll
    for (int kk = 0; kk < 4; ++kk) {
      bh8 b = *reinterpret_cast<const bh8*>(&F1F[((n0 * 4 + kk) << 9) + lane * 8]);
      acc = __builtin_amdgcn_mfma_f32_16x16x32_bf16(afrag[kk], b, acc, 0, 0, 0);
    }
    float bias = fc1b[n0 * 16 + lr];
#pragma unroll
    for (int r = 0; r < 4; ++r) {
      float v = acc[r] + bias;
      v = v > 0.f ? v : 0.f;
      float mk = ((bw[r][n0 >> 1] >> (((n0 & 1) << 4) + lr)) & 1u) ? 2.0f : 0.0f;
      ybuf[(wid * 16 + 4 * lg + r) * WPAD + n0 * 16 + lr] = f2bfbits(v * mk);
    }
  }
  wave_lds_fence();

  bh8 a2[4];
#pragma unroll
  for (int kk = 0; kk < 4; ++kk)
    a2[kk] = *reinterpret_cast<const bh8*>(
        &ybuf[(wid * 16 + lr) * WPAD + kk * 32 + 8 * lg]);

  // GEMM2 (N=64)
  fl4 acc2[4];
#pragma unroll
  for (int n0 = 0; n0 < 4; ++n0) {
    acc2[n0] = (fl4){0.f, 0.f, 0.f, 0.f};
#pragma unroll
    for (int kk = 0; kk < 4; ++kk) {
      bh8 b = *reinterpret_cast<const bh8*>(&F2F[((n0 * 4 + kk) << 9) + lane * 8]);
      acc2[n0] = __builtin_amdgcn_mfma_f32_16x16x32_bf16(a2[kk], b, acc2[n0], 0, 0, 0);
    }
    float bias = fc2b[n0 * 16 + lr];
#pragma unroll
    for (int r = 0; r < 4; ++r) acc2[n0][r] += bias;
  }

  // log_softmax over 64 cols + store
#pragma unroll
  for (int r = 0; r < 4; ++r) {
    float m = fmaxf(fmaxf(acc2[0][r], acc2[1][r]), fmaxf(acc2[2][r], acc2[3][r]));
#pragma unroll
    for (int d = 1; d < 16; d <<= 1) m = fmaxf(m, __shfl_xor(m, d, 16));
    float se = 0.f;
#pragma unroll
    for (int n0 = 0; n0 < 4; ++n0) se += __expf(acc2[n0][r] - m);
#pragma unroll
    for (int d = 1; d < 16; d <<= 1) se += __shfl_xor(se, d, 16);
    float lse = m + __logf(se);
    int row = row0 + wid * 16 + 4 * lg + r;
    if (row < N_NODES) {
#pragma unroll
      for (int n0 = 0; n0 < 4; ++n0)
        out[(long)row * DIM_OUT + n0 * 16 + lr] = acc2[n0][r] - lse;
    }
  }
}

// ---------------- launcher ----------------
extern "C" void kernel_launch(void* const* d_in, const int* in_sizes, int n_in,
                              void* d_out, int out_size, void* d_ws, size_t ws_size,
                              hipStream_t stream) {
  const float* x      = (const float*)d_in[0];
  const int*   ei     = (const int*)d_in[1];
  const float* cw1    = (const float*)d_in[2];
  const float* cb1    = (const float*)d_in[3];
  const float* cw2    = (const float*)d_in[4];
  const float* cb2    = (const float*)d_in[5];
  const float* gamma  = (const float*)d_in[6];
  const float* beta   = (const float*)d_in[7];
  const float* fc1w   = (const float*)d_in[8];
  const float* fc1b   = (const float*)d_in[9];
  const float* fc2w   = (const float*)d_in[10];
  const float* fc2b   = (const float*)d_in[11];
  const float* mask   = (const float*)d_in[12];
  float* out = (float*)d_out;

  char* ws = (char*)d_ws;
  unsigned short* aggB  = (unsigned short*)ws;                 // 25,600,000 B
  unsigned short* Zb    = (unsigned short*)(ws + 25600000);    // 25,600,000 B (xB alias)
  unsigned short* W1F   = (unsigned short*)(ws + 51200000);    //     98,304 B
  unsigned short* W2F   = (unsigned short*)(ws + 51298304);    //     98,304 B
  unsigned short* F1F   = (unsigned short*)(ws + 51396608);    //     32,768 B
  unsigned short* F2F   = (unsigned short*)(ws + 51429376);    //     16,384 B
  float*          stats = (float*)(ws + 51445760);             //      3,072 B
  int*            rowst = (int*)(ws + 51448832);               //    400,004 B
  int*            cursor= (int*)(ws + 51848836);               //    400,000 B
  int*            csr   = (int*)(ws + 52248836);               //  2,400,000 B
  int*            bsum  = (int*)(ws + 54648836);               //      1,564 B
  unsigned int*   bmask = (unsigned int*)(ws + 54651968);      //  1,600,000 B
  float*          sb    = (float*)(ws + 56251968);             //      3,072 B (3x256)
  if (ws_size < 56255040u) return;

  prep_kernel<<<NBLK, 256, 0, stream>>>(cw1, cw2, fc1w, fc2w, W1F, W2F, F1F, F2F,
                                        stats, cursor);        // cursor doubles as deg
  deg_xcast<<<12500, 256, 0, stream>>>(x, Zb, ei, cursor, mask, bmask); // xB -> Zb

  scanA<<<NBLK, 256, 0, stream>>>(cursor, rowst, bsum);
  scanC<<<NBLK, 256, 0, stream>>>(rowst, bsum, cursor);
  csr_fill<<<2344, 256, 0, stream>>>(ei, cursor, csr);

  // layer 0: gather bf16 x (in Zb) -> aggB; mlp overwrites Zb (xB dead)
  gather_h<0><<<25000, 256, 0, stream>>>(Zb, nullptr, rowst, csr, aggB);
  mlp_kernel<<<MLP_GRID, 256, 0, stream>>>(aggB, W1F, cb1, W2F, cb2, Zb, stats);
  bn_finalize<<<1, 128, 0, stream>>>(stats, gamma, beta, sb);

  // layer 1: uses sb0
  gather_h<1><<<25000, 256, 0, stream>>>(Zb, sb, rowst, csr, aggB);
  mlp_kernel<<<MLP_GRID, 256, 0, stream>>>(aggB, W1F + 16384, cb1 + 128, W2F + 16384,
                                           cb2 + 128, Zb, stats + 256);
  bn_finalize<<<1, 128, 0, stream>>>(stats + 256, gamma + 128, beta + 128, sb + 256);

  // layer 2: uses sb1
  gather_h<1><<<25000, 256, 0, stream>>>(Zb, sb + 256, rowst, csr, aggB);
  mlp_kernel<<<MLP_GRID, 256, 0, stream>>>(aggB, W1F + 32768, cb1 + 256, W2F + 32768,
                                           cb2 + 256, Zb, stats + 512);
  bn_finalize<<<1, 128, 0, stream>>>(stats + 512, gamma + 256, beta + 256, sb + 512);

  // head: uses sb2
  head_kernel<<<GRID64_HEAD, 256, 0, stream>>>(Zb, sb + 512,
                                               F1F, fc1b, F2F, fc2b, bmask, out);
}

// Round 12
// 311.120 us; speedup vs baseline: 1.6225x; 1.0126x over previous
//
#include <hip/hip_runtime.h>
#include <stdint.h>

#define N_NODES 100000
#define N_EDGES 600000
#define DIM_H   128
#define DIM_OUT 64
#define WPAD    136      // padded LDS row stride in ushort units (272B)
#define BN_EPS  1e-5f
#define NBLK    391      // ceil(N_NODES/256)
#define GRID64_HEAD 1563 // ceil(N_NODES/64)
#define MLP_GRID 782

typedef __attribute__((ext_vector_type(8))) __bf16        bh8;
typedef __attribute__((ext_vector_type(4))) float         fl4;
typedef __attribute__((ext_vector_type(8))) unsigned short us8;
typedef __attribute__((ext_vector_type(4))) unsigned short us4;

__device__ __forceinline__ unsigned short f2bfbits(float f) {
  unsigned int u = __builtin_bit_cast(unsigned int, f);
  u += 0x7fffu + ((u >> 16) & 1u);           // RNE
  return (unsigned short)(u >> 16);
}
__device__ __forceinline__ float bf2f(unsigned short b) {
  unsigned int u = ((unsigned int)b) << 16;
  return __builtin_bit_cast(float, u);
}
// in-wave LDS producer->consumer fence (lanes of the same wave only)
__device__ __forceinline__ void wave_lds_fence() {
  asm volatile("s_waitcnt lgkmcnt(0)" ::: "memory");
  __builtin_amdgcn_sched_barrier(0);
}

// ---------------- weight prep (fragment-linear layout) + zero stats/deg/dummy row ----------------
__global__ void prep_kernel(const float* __restrict__ cw1, const float* __restrict__ cw2,
                            const float* __restrict__ fc1w, const float* __restrict__ fc2w,
                            unsigned short* __restrict__ W1F, unsigned short* __restrict__ W2F,
                            unsigned short* __restrict__ F1F, unsigned short* __restrict__ F2F,
                            float* __restrict__ stats, int* __restrict__ deg,
                            unsigned short* __restrict__ zrow) {
  int t = blockIdx.x * 256 + threadIdx.x;
  if (t < 3 * 16384) {
    int l = t >> 14, o = t & 16383;
    int j = o & 7, lane = (o >> 3) & 63, kk = (o >> 9) & 3, n0 = o >> 11;
    int k = kk * 32 + ((lane >> 4) << 3) + j;
    int n = (n0 << 4) + (lane & 15);
    W1F[t] = f2bfbits(cw1[l * 16384 + k * 128 + n]);
    W2F[t] = f2bfbits(cw2[l * 16384 + k * 128 + n]);
  }
  if (t < 16384) {
    int o = t;
    int j = o & 7, lane = (o >> 3) & 63, kk = (o >> 9) & 3, n0 = o >> 11;
    int k = kk * 32 + ((lane >> 4) << 3) + j;
    int n = (n0 << 4) + (lane & 15);
    F1F[t] = f2bfbits(fc1w[k * 128 + n]);
  }
  if (t < 8192) {
    int o = t;
    int j = o & 7, lane = (o >> 3) & 63, kk = (o >> 9) & 3, n0 = o >> 11;
    int k = kk * 32 + ((lane >> 4) << 3) + j;
    int n = (n0 << 4) + (lane & 15);                 // n < 64
    F2F[t] = f2bfbits(fc2w[k * 64 + n]);
  }
  if (t < 768)   stats[t] = 0.f;
  if (t < 128)   zrow[t] = 0;                        // dummy zero row at H[N_NODES]
  if (t < N_NODES) deg[t] = 0;
}

// ---------------- x->bf16 cast + degree count + dropout bitmask pack ----------------
__global__ void deg_xcast(const float* __restrict__ x, unsigned short* __restrict__ xB,
                          const int* __restrict__ ei, int* __restrict__ deg,
                          const float* __restrict__ mask, unsigned int* __restrict__ bmask) {
  int i = blockIdx.x * 256 + threadIdx.x;    // 3.2M fl4 chunks exactly
  fl4 v = reinterpret_cast<const fl4*>(x)[i];
  us4 p;
#pragma unroll
  for (int j = 0; j < 4; ++j) p[j] = f2bfbits(v[j]);
  reinterpret_cast<us4*>(xB)[i] = p;
  if (i < N_EDGES) atomicAdd(&deg[ei[N_EDGES + i]], 1);
  if (i < N_NODES * 4) {                     // one dword of bitmask = 32 cols
    const float* mp = mask + (long)i * 32;
    unsigned int b = 0;
#pragma unroll
    for (int j8 = 0; j8 < 8; ++j8) {
      fl4 mv = *reinterpret_cast<const fl4*>(mp + j8 * 4);
      b |= (mv[0] > 0.f ? 1u : 0u) << (j8 * 4 + 0);
      b |= (mv[1] > 0.f ? 1u : 0u) << (j8 * 4 + 1);
      b |= (mv[2] > 0.f ? 1u : 0u) << (j8 * 4 + 2);
      b |= (mv[3] > 0.f ? 1u : 0u) << (j8 * 4 + 3);
    }
    bmask[i] = b;
  }
}

// ---------------- CSR build ----------------
__global__ void scanA(const int* __restrict__ deg, int* __restrict__ rowstart,
                      int* __restrict__ bsum) {
  __shared__ int s[256];
  int t = threadIdx.x, i = blockIdx.x * 256 + t;
  int v = (i < N_NODES) ? deg[i] : 0;
  s[t] = v;
  __syncthreads();
#pragma unroll
  for (int off = 1; off < 256; off <<= 1) {
    int u = (t >= off) ? s[t - off] : 0;
    __syncthreads();
    s[t] += u;
    __syncthreads();
  }
  if (i < N_NODES) rowstart[i] = s[t] - v;
  if (t == 0) bsum[blockIdx.x] = s[255];
}

// scanC with inline block-offset computation
__global__ void scanC(int* __restrict__ rowstart, const int* __restrict__ bsum,
                      int* __restrict__ cursor) {
  __shared__ int sred[256];
  int b = blockIdx.x, t = threadIdx.x;
  int partial = 0;
  for (int j = t; j < b; j += 256) partial += bsum[j];
  sred[t] = partial;
  __syncthreads();
#pragma unroll
  for (int off = 128; off > 0; off >>= 1) {
    if (t < off) sred[t] += sred[t + off];
    __syncthreads();
  }
  int boffb = sred[0];
  int i = b * 256 + t;
  if (i < N_NODES) {
    int v = rowstart[i] + boffb;
    rowstart[i] = v;
    cursor[i] = v;
  }
  if (i == 0) rowstart[N_NODES] = N_EDGES;
}

__global__ void csr_fill(const int* __restrict__ ei, int* __restrict__ cursor,
                         int* __restrict__ csr_src) {
  int e = blockIdx.x * 256 + threadIdx.x;
  if (e < N_EDGES) {
    int pos = atomicAdd(&cursor[ei[N_EDGES + e]], 1);
    csr_src[pos] = ei[e];
  }
}

// ---------------- BN finalize ----------------
__global__ void bn_finalize(const float* __restrict__ stats, const float* __restrict__ gamma,
                            const float* __restrict__ beta, float* __restrict__ sb) {
  int c = threadIdx.x;
  const float inv_n = 1.0f / (float)N_NODES;
  float mean = stats[c] * inv_n;
  float var  = stats[128 + c] * inv_n - mean * mean;
  float s = gamma[c] * rsqrtf(var + BN_EPS);
  sb[c] = s;
  sb[128 + c] = beta[c] - mean * s;
}

// ---------------- gather: one node per wave; quarter-wave = one 256B row ----------------
// Unconditional inner loads: out-of-range items map to the zero row at H[N_NODES].
template <int AFFINE>
__global__ __launch_bounds__(256)
void gather_h(const unsigned short* __restrict__ H, const float* __restrict__ sb,
              const int* __restrict__ rowstart, const int* __restrict__ csr,
              unsigned short* __restrict__ aggB) {
  int node = blockIdx.x * 4 + (threadIdx.x >> 6);   // grid*4 == N_NODES exactly
  int lane = threadIdx.x & 63;
  int q = lane >> 4, lc = lane & 15;
  int c = lc * 8;                        // 8 bf16 cols/lane; 16 lanes cover the row

  fl4 scA, scB, bcA, bcB;
  if (AFFINE) {
    scA = *reinterpret_cast<const fl4*>(sb + c);
    scB = *reinterpret_cast<const fl4*>(sb + c + 4);
    bcA = *reinterpret_cast<const fl4*>(sb + 128 + c);
    bcB = *reinterpret_cast<const fl4*>(sb + 128 + c + 4);
  }

  int nodeu = __builtin_amdgcn_readfirstlane(node);  // wave-uniform -> SGPR loads
  int rs = rowstart[nodeu], re = rowstart[nodeu + 1];
  int cnt = re - rs + 1;                 // {self} + neighbors
  float acc[8] = {0.f, 0.f, 0.f, 0.f, 0.f, 0.f, 0.f, 0.f};

  for (int base = 0; base < cnt; base += 64) {
    int item = base + lane;
    int myidx = (item == 0) ? nodeu
              : ((item < cnt) ? csr[rs + item - 1] : N_NODES);  // dummy zero row
    int lim = cnt - base; if (lim > 64) lim = 64;
    for (int sub = 0; sub < lim; sub += 8) {
      int i0 = __shfl(myidx, sub + q);
      int i1 = __shfl(myidx, sub + 4 + q);
      us8 r0 = *reinterpret_cast<const us8*>(H + (long)i0 * DIM_H + c);
      us8 r1 = *reinterpret_cast<const us8*>(H + (long)i1 * DIM_H + c);
#pragma unroll
      for (int j = 0; j < 8; ++j) acc[j] += bf2f(r0[j]) + bf2f(r1[j]);
    }
  }

#pragma unroll
  for (int j = 0; j < 8; ++j) {
    acc[j] += __shfl_xor(acc[j], 16);
    acc[j] += __shfl_xor(acc[j], 32);
  }

  if (q == 0) {
    us8 pk;
    if (AFFINE) {
      float fc = (float)cnt;
#pragma unroll
      for (int j = 0; j < 4; ++j) {
        pk[j]     = f2bfbits(scA[j] * acc[j]     + fc * bcA[j]);
        pk[4 + j] = f2bfbits(scB[j] * acc[4 + j] + fc * bcB[j]);
      }
    } else {
#pragma unroll
      for (int j = 0; j < 8; ++j) pk[j] = f2bfbits(acc[j]);
    }
    *reinterpret_cast<us8*>(aggB + (long)node * DIM_H + c) = pk;
  }
}

// ---------------- fused GIN MLP: fragment-linear LDS-staged weights ----------------
__global__ __launch_bounds__(256, 2)
void mlp_kernel(const unsigned short* __restrict__ A,
                const unsigned short* __restrict__ W1F, const float* __restrict__ b1,
                const unsigned short* __restrict__ W2F, const float* __restrict__ b2,
                unsigned short* __restrict__ Z, float* __restrict__ stats) {
  __shared__ __align__(16) unsigned short wbuf[16384];        // 32768 B, fragment-linear
  __shared__ __align__(16) unsigned short ybuf[128 * WPAD];   // 34816 B
  __shared__ float red[4][2][128];                            //  4096 B

  const int tid = threadIdx.x;
  const int wid = tid >> 6, lane = tid & 63;
  const int lr = lane & 15, lg = lane >> 4;
  const int row0 = blockIdx.x * 128;

  // A fragments straight from bf16 global (issue first; longest latency)
  bh8 afrag[2][4];
#pragma unroll
  for (int rt = 0; rt < 2; ++rt) {
    int row = row0 + wid * 32 + rt * 16 + lr;
    bool valid = row < N_NODES;
    const unsigned short* ap = A + (long)row * DIM_H;
#pragma unroll
    for (int kk = 0; kk < 4; ++kk) {
      us8 t = (us8)0;
      if (valid) t = *reinterpret_cast<const us8*>(ap + kk * 32 + 8 * lg);
      afrag[rt][kk] = __builtin_bit_cast(bh8, t);
    }
  }

  // stage W1F (linear copy, fully coalesced both sides)
#pragma unroll
  for (int i = 0; i < 8; ++i) {
    int ch = i * 256 + tid;
    *reinterpret_cast<uint4*>(&wbuf[ch * 8]) = *reinterpret_cast<const uint4*>(&W1F[ch * 8]);
  }
  __syncthreads();

  // GEMM1 + bias + relu -> ybuf (bf16); B from LDS, conflict-free 1KB bursts
#pragma unroll
  for (int n0 = 0; n0 < 8; ++n0) {
    fl4 acc[2] = {{0,0,0,0},{0,0,0,0}};
#pragma unroll
    for (int kk = 0; kk < 4; ++kk) {
      bh8 b = *reinterpret_cast<const bh8*>(&wbuf[((n0 * 4 + kk) << 9) + lane * 8]);
      acc[0] = __builtin_amdgcn_mfma_f32_16x16x32_bf16(afrag[0][kk], b, acc[0], 0, 0, 0);
      acc[1] = __builtin_amdgcn_mfma_f32_16x16x32_bf16(afrag[1][kk], b, acc[1], 0, 0, 0);
    }
    float bias = b1[n0 * 16 + lr];
#pragma unroll
    for (int rt = 0; rt < 2; ++rt)
#pragma unroll
      for (int r = 0; r < 4; ++r) {
        float v = acc[rt][r] + bias;
        v = v > 0.f ? v : 0.f;
        ybuf[(wid * 32 + rt * 16 + 4 * lg + r) * WPAD + n0 * 16 + lr] = f2bfbits(v);
      }
  }

  __syncthreads();           // all waves done reading W1 (and ybuf written)

  // stage W2F over wbuf
#pragma unroll
  for (int i = 0; i < 8; ++i) {
    int ch = i * 256 + tid;
    *reinterpret_cast<uint4*>(&wbuf[ch * 8]) = *reinterpret_cast<const uint4*>(&W2F[ch * 8]);
  }

  // A2 fragments from ybuf (own-wave rows, stable since prior barrier)
  bh8 a2[2][4];
#pragma unroll
  for (int rt = 0; rt < 2; ++rt)
#pragma unroll
    for (int kk = 0; kk < 4; ++kk)
      a2[rt][kk] = *reinterpret_cast<const bh8*>(
          &ybuf[(wid * 32 + rt * 16 + lr) * WPAD + kk * 32 + 8 * lg]);

  __syncthreads();           // W2 staged

  // GEMM2 + bias + relu -> ybuf (z), accumulate BN stats
#pragma unroll
  for (int n0 = 0; n0 < 8; ++n0) {
    fl4 acc[2] = {{0,0,0,0},{0,0,0,0}};
#pragma unroll
    for (int kk = 0; kk < 4; ++kk) {
      bh8 b = *reinterpret_cast<const bh8*>(&wbuf[((n0 * 4 + kk) << 9) + lane * 8]);
      acc[0] = __builtin_amdgcn_mfma_f32_16x16x32_bf16(a2[0][kk], b, acc[0], 0, 0, 0);
      acc[1] = __builtin_amdgcn_mfma_f32_16x16x32_bf16(a2[1][kk], b, acc[1], 0, 0, 0);
    }
    float bias = b2[n0 * 16 + lr];
    float sp = 0.f, qp = 0.f;
#pragma unroll
    for (int rt = 0; rt < 2; ++rt)
#pragma unroll
      for (int r = 0; r < 4; ++r) {
        int row = row0 + wid * 32 + rt * 16 + 4 * lg + r;
        float v = acc[rt][r] + bias;
        v = v > 0.f ? v : 0.f;
        ybuf[(wid * 32 + rt * 16 + 4 * lg + r) * WPAD + n0 * 16 + lr] = f2bfbits(v);
        if (row < N_NODES) { sp += v; qp += v * v; }
      }
    sp += __shfl_xor(sp, 16); sp += __shfl_xor(sp, 32);
    qp += __shfl_xor(qp, 16); qp += __shfl_xor(qp, 32);
    if (lg == 0) { red[wid][0][n0 * 16 + lr] = sp; red[wid][1][n0 * 16 + lr] = qp; }
  }

  wave_lds_fence();

  // per-wave coalesced z store (own 32 rows)
#pragma unroll
  for (int i = 0; i < 8; ++i) {
    int ch = i * 64 + lane;               // 0..511
    int r  = wid * 32 + (ch >> 4);
    int c8 = (ch & 15) << 3;
    int row = row0 + r;
    if (row < N_NODES)
      *reinterpret_cast<uint4*>(&Z[(long)row * DIM_H + c8]) =
          *reinterpret_cast<const uint4*>(&ybuf[r * WPAD + c8]);
  }

  __syncthreads();           // cross-wave stats reduce

  {
    int which = tid >> 7, cc = tid & 127;
    float v = red[0][which][cc] + red[1][which][cc] + red[2][which][cc] + red[3][which][cc];
    unsafeAtomicAdd(&stats[which * 128 + cc], v);
  }
}

// ---------------- head: BN-affine(sb) -> fc1 -> relu -> dropout(bitmask) -> fc2 -> log_softmax --
__global__ __launch_bounds__(256, 6)
void head_kernel(const unsigned short* __restrict__ Z, const float* __restrict__ sb,
                 const unsigned short* __restrict__ F1F, const float* __restrict__ fc1b,
                 const unsigned short* __restrict__ F2F, const float* __restrict__ fc2b,
                 const unsigned int* __restrict__ bmask, float* __restrict__ out) {
  __shared__ __align__(16) unsigned short ybuf[64 * WPAD];    // 17408 B

  const int tid = threadIdx.x;
  const int wid = tid >> 6, lane = tid & 63;
  const int lr = lane & 15, lg = lane >> 4;
  const int row0 = blockIdx.x * 64;

  // dropout bitmask for this lane's 4 output rows (128 bits each)
  unsigned int bw[4][4];
#pragma unroll
  for (int r = 0; r < 4; ++r) {
    int row = row0 + wid * 16 + 4 * lg + r;
    if (row < N_NODES) {
      uint4 t = *reinterpret_cast<const uint4*>(bmask + (long)row * 4);
      bw[r][0] = t.x; bw[r][1] = t.y; bw[r][2] = t.z; bw[r][3] = t.w;
    } else {
      bw[r][0] = bw[r][1] = bw[r][2] = bw[r][3] = 0u;
    }
  }

  // A fragments: affine(z) in bf16 with precomputed sb
  bh8 afrag[4];
#pragma unroll
  for (int kk = 0; kk < 4; ++kk) {
    int k0 = kk * 32 + 8 * lg;
    fl4 s0  = *reinterpret_cast<const fl4*>(sb + k0);
    fl4 s1  = *reinterpret_cast<const fl4*>(sb + k0 + 4);
    fl4 bb0 = *reinterpret_cast<const fl4*>(sb + 128 + k0);
    fl4 bb1 = *reinterpret_cast<const fl4*>(sb + 128 + k0 + 4);
    int row = row0 + wid * 16 + lr;
    us8 t = (us8)0;
    if (row < N_NODES) {
      us8 zv = *reinterpret_cast<const us8*>(Z + (long)row * DIM_H + k0);
#pragma unroll
      for (int j = 0; j < 4; ++j) {
        t[j]     = f2bfbits(bf2f(zv[j])     * s0[j] + bb0[j]);
        t[4 + j] = f2bfbits(bf2f(zv[4 + j]) * s1[j] + bb1[j]);
      }
    }
    afrag[kk] = __builtin_bit_cast(bh8, t);
  }

  // GEMM1 + fc1b + relu + dropout -> ybuf
#pragma unroll
  for (int n0 = 0; n0 < 8; ++n0) {
    fl4 acc = {0.f, 0.f, 0.f, 0.f};
#pragma unroll
    for (int kk = 0; kk < 4; ++kk) {
      bh8 b = *reinterpret_cast<const bh8*>(&F1F[((n0 * 4 + kk) << 9) + lane * 8]);
      acc = __builtin_amdgcn_mfma_f32_16x16x32_bf16(afrag[kk], b, acc, 0, 0, 0);
    }
    float bias = fc1b[n0 * 16 + lr];
#pragma unroll
    for (int r = 0; r < 4; ++r) {
      float v = acc[r] + bias;
      v = v > 0.f ? v : 0.f;
      float mk = ((bw[r][n0 >> 1] >> (((n0 & 1) << 4) + lr)) & 1u) ? 2.0f : 0.0f;
      ybuf[(wid * 16 + 4 * lg + r) * WPAD + n0 * 16 + lr] = f2bfbits(v * mk);
    }
  }
  wave_lds_fence();

  bh8 a2[4];
#pragma unroll
  for (int kk = 0; kk < 4; ++kk)
    a2[kk] = *reinterpret_cast<const bh8*>(
        &ybuf[(wid * 16 + lr) * WPAD + kk * 32 + 8 * lg]);

  // GEMM2 (N=64)
  fl4 acc2[4];
#pragma unroll
  for (int n0 = 0; n0 < 4; ++n0) {
    acc2[n0] = (fl4){0.f, 0.f, 0.f, 0.f};
#pragma unroll
    for (int kk = 0; kk < 4; ++kk) {
      bh8 b = *reinterpret_cast<const bh8*>(&F2F[((n0 * 4 + kk) << 9) + lane * 8]);
      acc2[n0] = __builtin_amdgcn_mfma_f32_16x16x32_bf16(a2[kk], b, acc2[n0], 0, 0, 0);
    }
    float bias = fc2b[n0 * 16 + lr];
#pragma unroll
    for (int r = 0; r < 4; ++r) acc2[n0][r] += bias;
  }

  // log_softmax over 64 cols + store
#pragma unroll
  for (int r = 0; r < 4; ++r) {
    float m = fmaxf(fmaxf(acc2[0][r], acc2[1][r]), fmaxf(acc2[2][r], acc2[3][r]));
#pragma unroll
    for (int d = 1; d < 16; d <<= 1) m = fmaxf(m, __shfl_xor(m, d, 16));
    float se = 0.f;
#pragma unroll
    for (int n0 = 0; n0 < 4; ++n0) se += __expf(acc2[n0][r] - m);
#pragma unroll
    for (int d = 1; d < 16; d <<= 1) se += __shfl_xor(se, d, 16);
    float lse = m + __logf(se);
    int row = row0 + wid * 16 + 4 * lg + r;
    if (row < N_NODES) {
#pragma unroll
      for (int n0 = 0; n0 < 4; ++n0)
        out[(long)row * DIM_OUT + n0 * 16 + lr] = acc2[n0][r] - lse;
    }
  }
}

// ---------------- launcher ----------------
extern "C" void kernel_launch(void* const* d_in, const int* in_sizes, int n_in,
                              void* d_out, int out_size, void* d_ws, size_t ws_size,
                              hipStream_t stream) {
  const float* x      = (const float*)d_in[0];
  const int*   ei     = (const int*)d_in[1];
  const float* cw1    = (const float*)d_in[2];
  const float* cb1    = (const float*)d_in[3];
  const float* cw2    = (const float*)d_in[4];
  const float* cb2    = (const float*)d_in[5];
  const float* gamma  = (const float*)d_in[6];
  const float* beta   = (const float*)d_in[7];
  const float* fc1w   = (const float*)d_in[8];
  const float* fc1b   = (const float*)d_in[9];
  const float* fc2w   = (const float*)d_in[10];
  const float* fc2b   = (const float*)d_in[11];
  const float* mask   = (const float*)d_in[12];
  float* out = (float*)d_out;

  char* ws = (char*)d_ws;
  unsigned short* aggB  = (unsigned short*)ws;                 // 25,600,000 B
  unsigned short* Zb    = (unsigned short*)(ws + 25600000);    // 25,600,256 B (100001 rows; xB alias)
  unsigned short* W1F   = (unsigned short*)(ws + 51200256);    //     98,304 B
  unsigned short* W2F   = (unsigned short*)(ws + 51298560);    //     98,304 B
  unsigned short* F1F   = (unsigned short*)(ws + 51396864);    //     32,768 B
  unsigned short* F2F   = (unsigned short*)(ws + 51429632);    //     16,384 B
  float*          stats = (float*)(ws + 51446016);             //      3,072 B
  int*            rowst = (int*)(ws + 51449088);               //    400,004 B
  int*            cursor= (int*)(ws + 51849092);               //    400,000 B
  int*            csr   = (int*)(ws + 52249092);               //  2,400,000 B
  int*            bsum  = (int*)(ws + 54649092);               //      1,564 B
  unsigned int*   bmask = (unsigned int*)(ws + 54650656);      //  1,600,000 B
  float*          sb    = (float*)(ws + 56250656);             //      3,072 B (3x256)
  if (ws_size < 56253728u) return;

  prep_kernel<<<NBLK, 256, 0, stream>>>(cw1, cw2, fc1w, fc2w, W1F, W2F, F1F, F2F,
                                        stats, cursor, Zb + (long)N_NODES * DIM_H);
  deg_xcast<<<12500, 256, 0, stream>>>(x, Zb, ei, cursor, mask, bmask); // xB -> Zb

  scanA<<<NBLK, 256, 0, stream>>>(cursor, rowst, bsum);
  scanC<<<NBLK, 256, 0, stream>>>(rowst, bsum, cursor);
  csr_fill<<<2344, 256, 0, stream>>>(ei, cursor, csr);

  // layer 0: gather bf16 x (in Zb) -> aggB; mlp overwrites Zb (xB dead)
  gather_h<0><<<25000, 256, 0, stream>>>(Zb, nullptr, rowst, csr, aggB);
  mlp_kernel<<<MLP_GRID, 256, 0, stream>>>(aggB, W1F, cb1, W2F, cb2, Zb, stats);
  bn_finalize<<<1, 128, 0, stream>>>(stats, gamma, beta, sb);

  // layer 1: uses sb0
  gather_h<1><<<25000, 256, 0, stream>>>(Zb, sb, rowst, csr, aggB);
  mlp_kernel<<<MLP_GRID, 256, 0, stream>>>(aggB, W1F + 16384, cb1 + 128, W2F + 16384,
                                           cb2 + 128, Zb, stats + 256);
  bn_finalize<<<1, 128, 0, stream>>>(stats + 256, gamma + 128, beta + 128, sb + 256);

  // layer 2: uses sb1
  gather_h<1><<<25000, 256, 0, stream>>>(Zb, sb + 256, rowst, csr, aggB);
  mlp_kernel<<<MLP_GRID, 256, 0, stream>>>(aggB, W1F + 32768, cb1 + 256, W2F + 32768,
                                           cb2 + 256, Zb, stats + 512);
  bn_finalize<<<1, 128, 0, stream>>>(stats + 512, gamma + 256, beta + 256, sb + 512);

  // head: uses sb2
  head_kernel<<<GRID64_HEAD, 256, 0, stream>>>(Zb, sb + 512,
                                               F1F, fc1b, F2F, fc2b, bmask, out);
}

// Round 13
// 309.571 us; speedup vs baseline: 1.6307x; 1.0050x over previous
//
#include <hip/hip_runtime.h>
#include <stdint.h>

#define N_NODES 100000
#define N_EDGES 600000
#define DIM_H   128
#define DIM_OUT 64
#define WPAD    136      // padded LDS row stride in ushort units (272B)
#define BN_EPS  1e-5f
#define NBLK    391      // ceil(N_NODES/256)
#define GRID64_HEAD 1563 // ceil(N_NODES/64)
#define MLP_GRID 782

typedef __attribute__((ext_vector_type(8))) __bf16        bh8;
typedef __attribute__((ext_vector_type(4))) float         fl4;
typedef __attribute__((ext_vector_type(8))) unsigned short us8;
typedef __attribute__((ext_vector_type(4))) unsigned short us4;

__device__ __forceinline__ unsigned short f2bfbits(float f) {
  unsigned int u = __builtin_bit_cast(unsigned int, f);
  u += 0x7fffu + ((u >> 16) & 1u);           // RNE
  return (unsigned short)(u >> 16);
}
__device__ __forceinline__ float bf2f(unsigned short b) {
  unsigned int u = ((unsigned int)b) << 16;
  return __builtin_bit_cast(float, u);
}
// in-wave LDS producer->consumer fence (lanes of the same wave only)
__device__ __forceinline__ void wave_lds_fence() {
  asm volatile("s_waitcnt lgkmcnt(0)" ::: "memory");
  __builtin_amdgcn_sched_barrier(0);
}

// ---------------- weight prep (fragment-linear layout) + zero stats/deg/dummy row ----------------
__global__ void prep_kernel(const float* __restrict__ cw1, const float* __restrict__ cw2,
                            const float* __restrict__ fc1w, const float* __restrict__ fc2w,
                            unsigned short* __restrict__ W1F, unsigned short* __restrict__ W2F,
                            unsigned short* __restrict__ F1F, unsigned short* __restrict__ F2F,
                            float* __restrict__ stats, int* __restrict__ deg,
                            unsigned short* __restrict__ zrow) {
  int t = blockIdx.x * 256 + threadIdx.x;
  if (t < 3 * 16384) {
    int l = t >> 14, o = t & 16383;
    int j = o & 7, lane = (o >> 3) & 63, kk = (o >> 9) & 3, n0 = o >> 11;
    int k = kk * 32 + ((lane >> 4) << 3) + j;
    int n = (n0 << 4) + (lane & 15);
    W1F[t] = f2bfbits(cw1[l * 16384 + k * 128 + n]);
    W2F[t] = f2bfbits(cw2[l * 16384 + k * 128 + n]);
  }
  if (t < 16384) {
    int o = t;
    int j = o & 7, lane = (o >> 3) & 63, kk = (o >> 9) & 3, n0 = o >> 11;
    int k = kk * 32 + ((lane >> 4) << 3) + j;
    int n = (n0 << 4) + (lane & 15);
    F1F[t] = f2bfbits(fc1w[k * 128 + n]);
  }
  if (t < 8192) {
    int o = t;
    int j = o & 7, lane = (o >> 3) & 63, kk = (o >> 9) & 3, n0 = o >> 11;
    int k = kk * 32 + ((lane >> 4) << 3) + j;
    int n = (n0 << 4) + (lane & 15);                 // n < 64
    F2F[t] = f2bfbits(fc2w[k * 64 + n]);
  }
  if (t < 768)   stats[t] = 0.f;
  if (t < 128)   zrow[t] = 0;                        // dummy zero row at H[N_NODES]
  if (t < N_NODES) deg[t] = 0;
}

// ---------------- x->bf16 cast + degree count + dropout bitmask pack ----------------
__global__ void deg_xcast(const float* __restrict__ x, unsigned short* __restrict__ xB,
                          const int* __restrict__ ei, int* __restrict__ deg,
                          const float* __restrict__ mask, unsigned int* __restrict__ bmask) {
  int i = blockIdx.x * 256 + threadIdx.x;    // 3.2M fl4 chunks exactly
  fl4 v = reinterpret_cast<const fl4*>(x)[i];
  us4 p;
#pragma unroll
  for (int j = 0; j < 4; ++j) p[j] = f2bfbits(v[j]);
  reinterpret_cast<us4*>(xB)[i] = p;
  if (i < N_EDGES) atomicAdd(&deg[ei[N_EDGES + i]], 1);
  if (i < N_NODES * 4) {                     // one dword of bitmask = 32 cols
    const float* mp = mask + (long)i * 32;
    unsigned int b = 0;
#pragma unroll
    for (int j8 = 0; j8 < 8; ++j8) {
      fl4 mv = *reinterpret_cast<const fl4*>(mp + j8 * 4);
      b |= (mv[0] > 0.f ? 1u : 0u) << (j8 * 4 + 0);
      b |= (mv[1] > 0.f ? 1u : 0u) << (j8 * 4 + 1);
      b |= (mv[2] > 0.f ? 1u : 0u) << (j8 * 4 + 2);
      b |= (mv[3] > 0.f ? 1u : 0u) << (j8 * 4 + 3);
    }
    bmask[i] = b;
  }
}

// ---------------- CSR build ----------------
__global__ void scanA(const int* __restrict__ deg, int* __restrict__ rowstart,
                      int* __restrict__ bsum) {
  __shared__ int s[256];
  int t = threadIdx.x, i = blockIdx.x * 256 + t;
  int v = (i < N_NODES) ? deg[i] : 0;
  s[t] = v;
  __syncthreads();
#pragma unroll
  for (int off = 1; off < 256; off <<= 1) {
    int u = (t >= off) ? s[t - off] : 0;
    __syncthreads();
    s[t] += u;
    __syncthreads();
  }
  if (i < N_NODES) rowstart[i] = s[t] - v;
  if (t == 0) bsum[blockIdx.x] = s[255];
}

// scanC with inline block-offset computation
__global__ void scanC(int* __restrict__ rowstart, const int* __restrict__ bsum,
                      int* __restrict__ cursor) {
  __shared__ int sred[256];
  int b = blockIdx.x, t = threadIdx.x;
  int partial = 0;
  for (int j = t; j < b; j += 256) partial += bsum[j];
  sred[t] = partial;
  __syncthreads();
#pragma unroll
  for (int off = 128; off > 0; off >>= 1) {
    if (t < off) sred[t] += sred[t + off];
    __syncthreads();
  }
  int boffb = sred[0];
  int i = b * 256 + t;
  if (i < N_NODES) {
    int v = rowstart[i] + boffb;
    rowstart[i] = v;
    cursor[i] = v;
  }
  if (i == 0) rowstart[N_NODES] = N_EDGES;
}

__global__ void csr_fill(const int* __restrict__ ei, int* __restrict__ cursor,
                         int* __restrict__ csr_src) {
  int e = blockIdx.x * 256 + threadIdx.x;
  if (e < N_EDGES) {
    int pos = atomicAdd(&cursor[ei[N_EDGES + e]], 1);
    csr_src[pos] = ei[e];
  }
}

// ---------------- BN finalize ----------------
__global__ void bn_finalize(const float* __restrict__ stats, const float* __restrict__ gamma,
                            const float* __restrict__ beta, float* __restrict__ sb) {
  int c = threadIdx.x;
  const float inv_n = 1.0f / (float)N_NODES;
  float mean = stats[c] * inv_n;
  float var  = stats[128 + c] * inv_n - mean * mean;
  float s = gamma[c] * rsqrtf(var + BN_EPS);
  sb[c] = s;
  sb[128 + c] = beta[c] - mean * s;
}

// ---------------- gather: one node per wave; quarter-wave = one 256B row ----------------
template <int AFFINE>
__global__ __launch_bounds__(256)
void gather_h(const unsigned short* __restrict__ H, const float* __restrict__ sb,
              const int* __restrict__ rowstart, const int* __restrict__ csr,
              unsigned short* __restrict__ aggB) {
  int node = blockIdx.x * 4 + (threadIdx.x >> 6);   // grid*4 == N_NODES exactly
  int lane = threadIdx.x & 63;
  int q = lane >> 4, lc = lane & 15;
  int c = lc * 8;                        // 8 bf16 cols/lane; 16 lanes cover the row

  fl4 scA, scB, bcA, bcB;
  if (AFFINE) {
    scA = *reinterpret_cast<const fl4*>(sb + c);
    scB = *reinterpret_cast<const fl4*>(sb + c + 4);
    bcA = *reinterpret_cast<const fl4*>(sb + 128 + c);
    bcB = *reinterpret_cast<const fl4*>(sb + 128 + c + 4);
  }

  int nodeu = __builtin_amdgcn_readfirstlane(node);  // wave-uniform -> SGPR loads
  int rs = rowstart[nodeu], re = rowstart[nodeu + 1];
  int cnt = re - rs + 1;                 // {self} + neighbors
  float acc[8] = {0.f, 0.f, 0.f, 0.f, 0.f, 0.f, 0.f, 0.f};

  for (int base = 0; base < cnt; base += 64) {
    int item = base + lane;
    int myidx = (item == 0) ? nodeu
              : ((item < cnt) ? csr[rs + item - 1] : N_NODES);  // dummy zero row
    int lim = cnt - base; if (lim > 64) lim = 64;
    for (int sub = 0; sub < lim; sub += 8) {
      int i0 = __shfl(myidx, sub + q);
      int i1 = __shfl(myidx, sub + 4 + q);
      us8 r0 = *reinterpret_cast<const us8*>(H + (long)i0 * DIM_H + c);
      us8 r1 = *reinterpret_cast<const us8*>(H + (long)i1 * DIM_H + c);
#pragma unroll
      for (int j = 0; j < 8; ++j) acc[j] += bf2f(r0[j]) + bf2f(r1[j]);
    }
  }

#pragma unroll
  for (int j = 0; j < 8; ++j) {
    acc[j] += __shfl_xor(acc[j], 16);
    acc[j] += __shfl_xor(acc[j], 32);
  }

  if (q == 0) {
    us8 pk;
    if (AFFINE) {
      float fc = (float)cnt;
#pragma unroll
      for (int j = 0; j < 4; ++j) {
        pk[j]     = f2bfbits(scA[j] * acc[j]     + fc * bcA[j]);
        pk[4 + j] = f2bfbits(scB[j] * acc[4 + j] + fc * bcB[j]);
      }
    } else {
#pragma unroll
      for (int j = 0; j < 8; ++j) pk[j] = f2bfbits(acc[j]);
    }
    *reinterpret_cast<us8*>(aggB + (long)node * DIM_H + c) = pk;
  }
}

// ---------------- fused GIN MLP: global-W with double-buffered B prefetch, 4 blocks/CU ----------
__global__ __launch_bounds__(256, 4)
void mlp_kernel(const unsigned short* __restrict__ A,
                const unsigned short* __restrict__ W1F, const float* __restrict__ b1,
                const unsigned short* __restrict__ W2F, const float* __restrict__ b2,
                unsigned short* __restrict__ Z, float* __restrict__ stats) {
  __shared__ __align__(16) unsigned short ybuf[128 * WPAD];   // 34816 B
  __shared__ float red[4][2][128];                            //  4096 B

  const int tid = threadIdx.x;
  const int wid = tid >> 6, lane = tid & 63;
  const int lr = lane & 15, lg = lane >> 4;
  const int row0 = blockIdx.x * 128;

  // A fragments (issue first; longest latency)
  bh8 afrag[2][4];
#pragma unroll
  for (int rt = 0; rt < 2; ++rt) {
    int row = row0 + wid * 32 + rt * 16 + lr;
    bool valid = row < N_NODES;
    const unsigned short* ap = A + (long)row * DIM_H;
#pragma unroll
    for (int kk = 0; kk < 4; ++kk) {
      us8 t = (us8)0;
      if (valid) t = *reinterpret_cast<const us8*>(ap + kk * 32 + 8 * lg);
      afrag[rt][kk] = __builtin_bit_cast(bh8, t);
    }
  }

  // preload all biases + first B tile
  float bias1[8], bias2[8];
#pragma unroll
  for (int n0 = 0; n0 < 8; ++n0) { bias1[n0] = b1[n0 * 16 + lr]; bias2[n0] = b2[n0 * 16 + lr]; }

  bh8 bnxt[4];
#pragma unroll
  for (int kk = 0; kk < 4; ++kk)
    bnxt[kk] = *reinterpret_cast<const bh8*>(&W1F[(kk << 9) + lane * 8]);

  // GEMM1 + bias + relu -> ybuf (B double-buffered: n0+1 loads issued before n0 MFMAs)
#pragma unroll
  for (int n0 = 0; n0 < 8; ++n0) {
    bh8 bc[4];
#pragma unroll
    for (int kk = 0; kk < 4; ++kk) bc[kk] = bnxt[kk];
    if (n0 < 7) {
#pragma unroll
      for (int kk = 0; kk < 4; ++kk)
        bnxt[kk] = *reinterpret_cast<const bh8*>(&W1F[(((n0 + 1) * 4 + kk) << 9) + lane * 8]);
    }
    fl4 acc[2] = {{0,0,0,0},{0,0,0,0}};
#pragma unroll
    for (int kk = 0; kk < 4; ++kk) {
      acc[0] = __builtin_amdgcn_mfma_f32_16x16x32_bf16(afrag[0][kk], bc[kk], acc[0], 0, 0, 0);
      acc[1] = __builtin_amdgcn_mfma_f32_16x16x32_bf16(afrag[1][kk], bc[kk], acc[1], 0, 0, 0);
    }
#pragma unroll
    for (int rt = 0; rt < 2; ++rt)
#pragma unroll
      for (int r = 0; r < 4; ++r) {
        float v = acc[rt][r] + bias1[n0];
        v = v > 0.f ? v : 0.f;
        ybuf[(wid * 32 + rt * 16 + 4 * lg + r) * WPAD + n0 * 16 + lr] = f2bfbits(v);
      }
  }

  // prefetch first W2 tile (global; independent of LDS fences below)
#pragma unroll
  for (int kk = 0; kk < 4; ++kk)
    bnxt[kk] = *reinterpret_cast<const bh8*>(&W2F[(kk << 9) + lane * 8]);

  wave_lds_fence();          // ybuf writes visible to own wave

  // A2 fragments from ybuf (own-wave rows)
  bh8 a2[2][4];
#pragma unroll
  for (int rt = 0; rt < 2; ++rt)
#pragma unroll
    for (int kk = 0; kk < 4; ++kk)
      a2[rt][kk] = *reinterpret_cast<const bh8*>(
          &ybuf[(wid * 32 + rt * 16 + lr) * WPAD + kk * 32 + 8 * lg]);

  wave_lds_fence();          // a2 in regs before ybuf overwrite

  // GEMM2 + bias + relu -> ybuf (z), accumulate BN stats
#pragma unroll
  for (int n0 = 0; n0 < 8; ++n0) {
    bh8 bc[4];
#pragma unroll
    for (int kk = 0; kk < 4; ++kk) bc[kk] = bnxt[kk];
    if (n0 < 7) {
#pragma unroll
      for (int kk = 0; kk < 4; ++kk)
        bnxt[kk] = *reinterpret_cast<const bh8*>(&W2F[(((n0 + 1) * 4 + kk) << 9) + lane * 8]);
    }
    fl4 acc[2] = {{0,0,0,0},{0,0,0,0}};
#pragma unroll
    for (int kk = 0; kk < 4; ++kk) {
      acc[0] = __builtin_amdgcn_mfma_f32_16x16x32_bf16(a2[0][kk], bc[kk], acc[0], 0, 0, 0);
      acc[1] = __builtin_amdgcn_mfma_f32_16x16x32_bf16(a2[1][kk], bc[kk], acc[1], 0, 0, 0);
    }
    float sp = 0.f, qp = 0.f;
#pragma unroll
    for (int rt = 0; rt < 2; ++rt)
#pragma unroll
      for (int r = 0; r < 4; ++r) {
        int row = row0 + wid * 32 + rt * 16 + 4 * lg + r;
        float v = acc[rt][r] + bias2[n0];
        v = v > 0.f ? v : 0.f;
        ybuf[(wid * 32 + rt * 16 + 4 * lg + r) * WPAD + n0 * 16 + lr] = f2bfbits(v);
        if (row < N_NODES) { sp += v; qp += v * v; }
      }
    sp += __shfl_xor(sp, 16); sp += __shfl_xor(sp, 32);
    qp += __shfl_xor(qp, 16); qp += __shfl_xor(qp, 32);
    if (lg == 0) { red[wid][0][n0 * 16 + lr] = sp; red[wid][1][n0 * 16 + lr] = qp; }
  }

  wave_lds_fence();

  // per-wave coalesced z store (own 32 rows)
#pragma unroll
  for (int i = 0; i < 8; ++i) {
    int ch = i * 64 + lane;               // 0..511
    int r  = wid * 32 + (ch >> 4);
    int c8 = (ch & 15) << 3;
    int row = row0 + r;
    if (row < N_NODES)
      *reinterpret_cast<uint4*>(&Z[(long)row * DIM_H + c8]) =
          *reinterpret_cast<const uint4*>(&ybuf[r * WPAD + c8]);
  }

  __syncthreads();           // cross-wave stats reduce

  {
    int which = tid >> 7, cc = tid & 127;
    float v = red[0][which][cc] + red[1][which][cc] + red[2][which][cc] + red[3][which][cc];
    unsafeAtomicAdd(&stats[which * 128 + cc], v);
  }
}

// ---------------- head: BN-affine(sb) -> fc1 -> relu -> dropout(bitmask) -> fc2 -> log_softmax --
__global__ __launch_bounds__(256, 6)
void head_kernel(const unsigned short* __restrict__ Z, const float* __restrict__ sb,
                 const unsigned short* __restrict__ F1F, const float* __restrict__ fc1b,
                 const unsigned short* __restrict__ F2F, const float* __restrict__ fc2b,
                 const unsigned int* __restrict__ bmask, float* __restrict__ out) {
  __shared__ __align__(16) unsigned short ybuf[64 * WPAD];    // 17408 B

  const int tid = threadIdx.x;
  const int wid = tid >> 6, lane = tid & 63;
  const int lr = lane & 15, lg = lane >> 4;
  const int row0 = blockIdx.x * 64;

  // dropout bitmask for this lane's 4 output rows (128 bits each)
  unsigned int bw[4][4];
#pragma unroll
  for (int r = 0; r < 4; ++r) {
    int row = row0 + wid * 16 + 4 * lg + r;
    if (row < N_NODES) {
      uint4 t = *reinterpret_cast<const uint4*>(bmask + (long)row * 4);
      bw[r][0] = t.x; bw[r][1] = t.y; bw[r][2] = t.z; bw[r][3] = t.w;
    } else {
      bw[r][0] = bw[r][1] = bw[r][2] = bw[r][3] = 0u;
    }
  }

  // biases preload
  float bias1[8], bias2[4];
#pragma unroll
  for (int n0 = 0; n0 < 8; ++n0) bias1[n0] = fc1b[n0 * 16 + lr];
#pragma unroll
  for (int n0 = 0; n0 < 4; ++n0) bias2[n0] = fc2b[n0 * 16 + lr];

  // A fragments: affine(z) in bf16 with precomputed sb
  bh8 afrag[4];
#pragma unroll
  for (int kk = 0; kk < 4; ++kk) {
    int k0 = kk * 32 + 8 * lg;
    fl4 s0  = *reinterpret_cast<const fl4*>(sb + k0);
    fl4 s1  = *reinterpret_cast<const fl4*>(sb + k0 + 4);
    fl4 bb0 = *reinterpret_cast<const fl4*>(sb + 128 + k0);
    fl4 bb1 = *reinterpret_cast<const fl4*>(sb + 128 + k0 + 4);
    int row = row0 + wid * 16 + lr;
    us8 t = (us8)0;
    if (row < N_NODES) {
      us8 zv = *reinterpret_cast<const us8*>(Z + (long)row * DIM_H + k0);
#pragma unroll
      for (int j = 0; j < 4; ++j) {
        t[j]     = f2bfbits(bf2f(zv[j])     * s0[j] + bb0[j]);
        t[4 + j] = f2bfbits(bf2f(zv[4 + j]) * s1[j] + bb1[j]);
      }
    }
    afrag[kk] = __builtin_bit_cast(bh8, t);
  }

  // GEMM1 + fc1b + relu + dropout -> ybuf (B double-buffered)
  bh8 bnxt[4];
#pragma unroll
  for (int kk = 0; kk < 4; ++kk)
    bnxt[kk] = *reinterpret_cast<const bh8*>(&F1F[(kk << 9) + lane * 8]);
#pragma unroll
  for (int n0 = 0; n0 < 8; ++n0) {
    bh8 bc[4];
#pragma unroll
    for (int kk = 0; kk < 4; ++kk) bc[kk] = bnxt[kk];
    if (n0 < 7) {
#pragma unroll
      for (int kk = 0; kk < 4; ++kk)
        bnxt[kk] = *reinterpret_cast<const bh8*>(&F1F[(((n0 + 1) * 4 + kk) << 9) + lane * 8]);
    }
    fl4 acc = {0.f, 0.f, 0.f, 0.f};
#pragma unroll
    for (int kk = 0; kk < 4; ++kk)
      acc = __builtin_amdgcn_mfma_f32_16x16x32_bf16(afrag[kk], bc[kk], acc, 0, 0, 0);
#pragma unroll
    for (int r = 0; r < 4; ++r) {
      float v = acc[r] + bias1[n0];
      v = v > 0.f ? v : 0.f;
      float mk = ((bw[r][n0 >> 1] >> (((n0 & 1) << 4) + lr)) & 1u) ? 2.0f : 0.0f;
      ybuf[(wid * 16 + 4 * lg + r) * WPAD + n0 * 16 + lr] = f2bfbits(v * mk);
    }
  }

  // prefetch first F2 tile before fences
#pragma unroll
  for (int kk = 0; kk < 4; ++kk)
    bnxt[kk] = *reinterpret_cast<const bh8*>(&F2F[(kk << 9) + lane * 8]);

  wave_lds_fence();

  bh8 a2[4];
#pragma unroll
  for (int kk = 0; kk < 4; ++kk)
    a2[kk] = *reinterpret_cast<const bh8*>(
        &ybuf[(wid * 16 + lr) * WPAD + kk * 32 + 8 * lg]);

  // GEMM2 (N=64), B double-buffered
  fl4 acc2[4];
#pragma unroll
  for (int n0 = 0; n0 < 4; ++n0) {
    bh8 bc[4];
#pragma unroll
    for (int kk = 0; kk < 4; ++kk) bc[kk] = bnxt[kk];
    if (n0 < 3) {
#pragma unroll
      for (int kk = 0; kk < 4; ++kk)
        bnxt[kk] = *reinterpret_cast<const bh8*>(&F2F[(((n0 + 1) * 4 + kk) << 9) + lane * 8]);
    }
    acc2[n0] = (fl4){0.f, 0.f, 0.f, 0.f};
#pragma unroll
    for (int kk = 0; kk < 4; ++kk)
      acc2[n0] = __builtin_amdgcn_mfma_f32_16x16x32_bf16(a2[kk], bc[kk], acc2[n0], 0, 0, 0);
#pragma unroll
    for (int r = 0; r < 4; ++r) acc2[n0][r] += bias2[n0];
  }

  // log_softmax over 64 cols + store
#pragma unroll
  for (int r = 0; r < 4; ++r) {
    float m = fmaxf(fmaxf(acc2[0][r], acc2[1][r]), fmaxf(acc2[2][r], acc2[3][r]));
#pragma unroll
    for (int d = 1; d < 16; d <<= 1) m = fmaxf(m, __shfl_xor(m, d, 16));
    float se = 0.f;
#pragma unroll
    for (int n0 = 0; n0 < 4; ++n0) se += __expf(acc2[n0][r] - m);
#pragma unroll
    for (int d = 1; d < 16; d <<= 1) se += __shfl_xor(se, d, 16);
    float lse = m + __logf(se);
    int row = row0 + wid * 16 + 4 * lg + r;
    if (row < N_NODES) {
#pragma unroll
      for (int n0 = 0; n0 < 4; ++n0)
        out[(long)row * DIM_OUT + n0 * 16 + lr] = acc2[n0][r] - lse;
    }
  }
}

// ---------------- launcher ----------------
extern "C" void kernel_launch(void* const* d_in, const int* in_sizes, int n_in,
                              void* d_out, int out_size, void* d_ws, size_t ws_size,
                              hipStream_t stream) {
  const float* x      = (const float*)d_in[0];
  const int*   ei     = (const int*)d_in[1];
  const float* cw1    = (const float*)d_in[2];
  const float* cb1    = (const float*)d_in[3];
  const float* cw2    = (const float*)d_in[4];
  const float* cb2    = (const float*)d_in[5];
  const float* gamma  = (const float*)d_in[6];
  const float* beta   = (const float*)d_in[7];
  const float* fc1w   = (const float*)d_in[8];
  const float* fc1b   = (const float*)d_in[9];
  const float* fc2w   = (const float*)d_in[10];
  const float* fc2b   = (const float*)d_in[11];
  const float* mask   = (const float*)d_in[12];
  float* out = (float*)d_out;

  char* ws = (char*)d_ws;
  unsigned short* aggB  = (unsigned short*)ws;                 // 25,600,000 B
  unsigned short* Zb    = (unsigned short*)(ws + 25600000);    // 25,600,256 B (100001 rows; xB alias)
  unsigned short* W1F   = (unsigned short*)(ws + 51200256);    //     98,304 B
  unsigned short* W2F   = (unsigned short*)(ws + 51298560);    //     98,304 B
  unsigned short* F1F   = (unsigned short*)(ws + 51396864);    //     32,768 B
  unsigned short* F2F   = (unsigned short*)(ws + 51429632);    //     16,384 B
  float*          stats = (float*)(ws + 51446016);             //      3,072 B
  int*            rowst = (int*)(ws + 51449088);               //    400,004 B
  int*            cursor= (int*)(ws + 51849092);               //    400,000 B
  int*            csr   = (int*)(ws + 52249092);               //  2,400,000 B
  int*            bsum  = (int*)(ws + 54649092);               //      1,564 B
  unsigned int*   bmask = (unsigned int*)(ws + 54650656);      //  1,600,000 B
  float*          sb    = (float*)(ws + 56250656);             //      3,072 B (3x256)
  if (ws_size < 56253728u) return;

  prep_kernel<<<NBLK, 256, 0, stream>>>(cw1, cw2, fc1w, fc2w, W1F, W2F, F1F, F2F,
                                        stats, cursor, Zb + (long)N_NODES * DIM_H);
  deg_xcast<<<12500, 256, 0, stream>>>(x, Zb, ei, cursor, mask, bmask); // xB -> Zb

  scanA<<<NBLK, 256, 0, stream>>>(cursor, rowst, bsum);
  scanC<<<NBLK, 256, 0, stream>>>(rowst, bsum, cursor);
  csr_fill<<<2344, 256, 0, stream>>>(ei, cursor, csr);

  // layer 0: gather bf16 x (in Zb) -> aggB; mlp overwrites Zb (xB dead)
  gather_h<0><<<25000, 256, 0, stream>>>(Zb, nullptr, rowst, csr, aggB);
  mlp_kernel<<<MLP_GRID, 256, 0, stream>>>(aggB, W1F, cb1, W2F, cb2, Zb, stats);
  bn_finalize<<<1, 128, 0, stream>>>(stats, gamma, beta, sb);

  // layer 1: uses sb0
  gather_h<1><<<25000, 256, 0, stream>>>(Zb, sb, rowst, csr, aggB);
  mlp_kernel<<<MLP_GRID, 256, 0, stream>>>(aggB, W1F + 16384, cb1 + 128, W2F + 16384,
                                           cb2 + 128, Zb, stats + 256);
  bn_finalize<<<1, 128, 0, stream>>>(stats + 256, gamma + 128, beta + 128, sb + 256);

  // layer 2: uses sb1
  gather_h<1><<<25000, 256, 0, stream>>>(Zb, sb + 256, rowst, csr, aggB);
  mlp_kernel<<<MLP_GRID, 256, 0, stream>>>(aggB, W1F + 32768, cb1 + 256, W2F + 32768,
                                           cb2 + 256, Zb, stats + 512);
  bn_finalize<<<1, 128, 0, stream>>>(stats + 512, gamma + 256, beta + 256, sb + 512);

  // head: uses sb2
  head_kernel<<<GRID64_HEAD, 256, 0, stream>>>(Zb, sb + 512,
                                               F1F, fc1b, F2F, fc2b, bmask, out);
}